// Round 7
// baseline (1189.638 us; speedup 1.0000x reference)
//
#include <hip/hip_runtime.h>
#include <math.h>

#define NN 100000
#define NE 600000
#define NG 64
#define HD 128
#define NL 6
#define NB 1563   // fused blocks = ceil(NN/64)
#define PSL 16    // pool slices per graph

typedef unsigned short ushort_t;

__device__ __forceinline__ float bf2f(ushort_t u) {
    return __uint_as_float(((unsigned)u) << 16);
}
__device__ __forceinline__ ushort_t f2bf(float f) {
    unsigned u = __float_as_uint(f);
    unsigned r = (u + 0x7fffu + ((u >> 16) & 1u)) >> 16;   // round-to-nearest-even
    return (ushort_t)r;
}

// ---------------- x -> bf16 cast (once per call) ----------------

__global__ __launch_bounds__(256) void k_cast(const float* __restrict__ x,
                                              ushort_t* __restrict__ xb) {
    int i = blockIdx.x * 256 + threadIdx.x;   // one float4 -> ushort4 per thread
    if (i < NN * 32) {
        float4 v = ((const float4*)x)[i];
        ((ushort4*)xb)[i] = make_ushort4(f2bf(v.x), f2bf(v.y), f2bf(v.z), f2bf(v.w));
    }
}

// ---------------- CSR build ----------------

__global__ __launch_bounds__(256) void k_hist(const int* __restrict__ ei, int* __restrict__ counts) {
    int e = blockIdx.x * 256 + threadIdx.x;
    if (e < NE) atomicAdd(&counts[ei[NE + e]], 1);
}

__global__ __launch_bounds__(256) void k_scan1(const int* __restrict__ counts, int* __restrict__ bsums) {
    __shared__ int s[256];
    int i = blockIdx.x * 256 + threadIdx.x;
    s[threadIdx.x] = (i < NN) ? counts[i] : 0;
    __syncthreads();
    for (int off = 128; off > 0; off >>= 1) {
        if (threadIdx.x < off) s[threadIdx.x] += s[threadIdx.x + off];
        __syncthreads();
    }
    if (threadIdx.x == 0) bsums[blockIdx.x] = s[0];
}

__global__ __launch_bounds__(512) void k_scan2(int* __restrict__ bsums, int nb) {
    __shared__ int s[512];
    int t = threadIdx.x;
    s[t] = (t < nb) ? bsums[t] : 0;
    __syncthreads();
    for (int off = 1; off < 512; off <<= 1) {
        int v = (t >= off) ? s[t - off] : 0;
        __syncthreads();
        s[t] += v;
        __syncthreads();
    }
    if (t < nb) bsums[t] = (t == 0) ? 0 : s[t - 1];
}

__global__ __launch_bounds__(256) void k_scan3(const int* __restrict__ counts, const int* __restrict__ bsums,
                                               int* __restrict__ rowptr) {
    __shared__ int s[256];
    int t = threadIdx.x;
    int i = blockIdx.x * 256 + t;
    int v = (i < NN) ? counts[i] : 0;
    s[t] = v;
    __syncthreads();
    for (int off = 1; off < 256; off <<= 1) {
        int u = (t >= off) ? s[t - off] : 0;
        __syncthreads();
        s[t] += u;
        __syncthreads();
    }
    if (i < NN) rowptr[i] = bsums[blockIdx.x] + s[t] - v;
    if (i == 0) rowptr[NN] = NE;
}

__global__ __launch_bounds__(256) void k_fill(const int* __restrict__ ei, const int* __restrict__ rowptr,
                                              int* __restrict__ cursor, int* __restrict__ colsrc) {
    int e = blockIdx.x * 256 + threadIdx.x;
    if (e < NE) {
        int d = ei[NE + e];
        int pos = rowptr[d] + atomicAdd(&cursor[d], 1);
        colsrc[pos] = ei[e];
    }
}

// ---------------- Fused layer: gather(+BN affine) -> LDS -> GEMM -> relu -> bf16 ----
// Each block owns 64 dst rows. Phase 1: its 4 waves gather 16 rows each from bf16
// h_in (applying prev layer's deferred BN affine analytically), writing straight
// into the transposed+XOR-swizzled At tile (no tbuf round-trip: saves 102 MB/layer).
// Phase 2: same GEMM as before (Ws staged in 16 KB quarters, 48 KB LDS total,
// 3 blocks/CU). Reads old h buffer, writes new one (ping-pong; no in-place race).

__global__ __launch_bounds__(256) void k_fused(
    const ushort_t* __restrict__ hin,
    const int* __restrict__ rowptr, const int* __restrict__ colsrc,
    const float* __restrict__ stats, const float* __restrict__ bng,
    const float* __restrict__ bnb,
    const float* __restrict__ W, const float* __restrict__ bias,
    ushort_t* __restrict__ hout, float* __restrict__ partials) {
    __shared__ float At[128 * 64];   // [k][r^swz]  32 KB
    __shared__ float Ws[32 * 128];   // [kk][c]     16 KB
    int t = threadIdx.x;
    int wave = t >> 6, lane = t & 63;
    int row0 = blockIdx.x * 64;

    // deferred BN affine for this lane's two features (wave-uniform per lane)
    float sc0 = 1.f, sc1 = 1.f, sh0 = 0.f, sh1 = 0.f;
    if (stats != nullptr) {
        int c0 = lane * 2;
        const float inv_n = 1.0f / (float)NN;
        float m0 = stats[c0] * inv_n, m1 = stats[c0 + 1] * inv_n;
        float var0 = fmaf(-m0, m0, stats[HD + c0] * inv_n);
        float var1 = fmaf(-m1, m1, stats[HD + c0 + 1] * inv_n);
        sc0 = bng[c0] * rsqrtf(var0 + 1e-5f);
        sc1 = bng[c0 + 1] * rsqrtf(var1 + 1e-5f);
        sh0 = bnb[c0] - m0 * sc0;
        sh1 = bnb[c0 + 1] - m1 * sc1;
    }

    // Phase 1: gather 16 rows per wave into At
    const ushort2* h2 = (const ushort2*)hin;
    int k0 = 2 * lane, k1 = 2 * lane + 1;
    int swz = 8 * ((lane >> 1) & 7);   // == 8*((k0>>2)&7) == 8*((k1>>2)&7)
    #pragma unroll 1
    for (int rr = 0; rr < 16; ++rr) {
        int r = wave * 16 + rr;
        int row = row0 + r;
        float ox = 0.f, oy = 0.f;
        if (row < NN) {
            int beg = rowptr[row], end = rowptr[row + 1];
            float ax = 0.f, ay = 0.f;
            int e = beg;
            for (; e + 3 < end; e += 4) {
                int s0 = colsrc[e];
                int s1 = colsrc[e + 1];
                int s2 = colsrc[e + 2];
                int s3 = colsrc[e + 3];
                ushort2 v0 = h2[(size_t)s0 * 64 + lane];
                ushort2 v1 = h2[(size_t)s1 * 64 + lane];
                ushort2 v2 = h2[(size_t)s2 * 64 + lane];
                ushort2 v3 = h2[(size_t)s3 * 64 + lane];
                ax += (bf2f(v0.x) + bf2f(v1.x)) + (bf2f(v2.x) + bf2f(v3.x));
                ay += (bf2f(v0.y) + bf2f(v1.y)) + (bf2f(v2.y) + bf2f(v3.y));
            }
            for (; e < end; ++e) {
                int s0 = colsrc[e];
                ushort2 v0 = h2[(size_t)s0 * 64 + lane];
                ax += bf2f(v0.x);
                ay += bf2f(v0.y);
            }
            float deg = (float)(end - beg);
            ox = fmaf(sc0, ax, deg * sh0);
            oy = fmaf(sc1, ay, deg * sh1);
        }
        int rs = r ^ swz;
        At[k0 * 64 + rs] = ox;
        At[k1 * 64 + rs] = oy;
    }
    __syncthreads();

    // Phase 2: GEMM
    int rg = t & 15, cg = t >> 4;
    int r0 = 4 * rg, c0 = 8 * cg;
    float acc[4][8];
    #pragma unroll
    for (int i = 0; i < 4; ++i)
        #pragma unroll
        for (int j = 0; j < 8; ++j) acc[i][j] = 0.f;

    #pragma unroll
    for (int q = 0; q < 4; ++q) {
        if (q) __syncthreads();
        const float4* Wq = (const float4*)(W + q * 32 * 128);
        #pragma unroll
        for (int it = 0; it < 4; ++it) {
            int id = t + 256 * it;
            ((float4*)Ws)[id] = Wq[id];
        }
        __syncthreads();
        #pragma unroll 4
        for (int kk = 0; kk < 32; ++kk) {
            int k = q * 32 + kk;
            float4 a = *(const float4*)&At[k * 64 + (r0 ^ (8 * ((k >> 2) & 7)))];
            const float4* wp = (const float4*)&Ws[kk * 128 + c0];
            float4 w0 = wp[0];
            float4 w1 = wp[1];
            float av[4] = {a.x, a.y, a.z, a.w};
            float wv[8] = {w0.x, w0.y, w0.z, w0.w, w1.x, w1.y, w1.z, w1.w};
            #pragma unroll
            for (int i = 0; i < 4; ++i)
                #pragma unroll
                for (int j = 0; j < 8; ++j) acc[i][j] = fmaf(av[i], wv[j], acc[i][j]);
        }
    }

    float bsv[8];
    #pragma unroll
    for (int j = 0; j < 8; ++j) bsv[j] = bias[c0 + j];
    float lsum[8], lsq[8];
    #pragma unroll
    for (int j = 0; j < 8; ++j) { lsum[j] = 0.f; lsq[j] = 0.f; }
    #pragma unroll
    for (int i = 0; i < 4; ++i) {
        int row = row0 + r0 + i;
        if (row < NN) {
            ushort_t hv[8];
            #pragma unroll
            for (int j = 0; j < 8; ++j) {
                float v = fmaxf(acc[i][j] + bsv[j], 0.f);
                ushort_t b = f2bf(v);
                hv[j] = b;
                float vr = bf2f(b);      // stats on the rounded value
                lsum[j] += vr;
                lsq[j] = fmaf(vr, vr, lsq[j]);
            }
            ushort4* dst = (ushort4*)&hout[(size_t)row * 128 + c0];
            dst[0] = make_ushort4(hv[0], hv[1], hv[2], hv[3]);
            dst[1] = make_ushort4(hv[4], hv[5], hv[6], hv[7]);
        }
    }
    #pragma unroll
    for (int off = 1; off < 16; off <<= 1) {
        #pragma unroll
        for (int j = 0; j < 8; ++j) {
            lsum[j] += __shfl_xor(lsum[j], off, 64);
            lsq[j] += __shfl_xor(lsq[j], off, 64);
        }
    }
    if (rg == 0) {
        float* pr = partials + (size_t)blockIdx.x * 256;
        float4* p0 = (float4*)&pr[c0];
        p0[0] = make_float4(lsum[0], lsum[1], lsum[2], lsum[3]);
        p0[1] = make_float4(lsum[4], lsum[5], lsum[6], lsum[7]);
        float4* p1 = (float4*)&pr[HD + c0];
        p1[0] = make_float4(lsq[0], lsq[1], lsq[2], lsq[3]);
        p1[1] = make_float4(lsq[4], lsq[5], lsq[6], lsq[7]);
    }
}

// ---------------- Partial-stats reduction: 1563 x 256 -> 256 ----------------

__global__ __launch_bounds__(256) void k_red(const float* __restrict__ partials,
                                             float* __restrict__ stats) {
    int t = threadIdx.x;
    float s = 0.f;
    for (int r = blockIdx.x; r < NB; r += 16) s += partials[(size_t)r * 256 + t];
    atomicAdd(&stats[t], s);
}

// ---------------- Pooling, phase 1: per-(graph,slice) partial sums (bf16 h) ---------

__device__ __forceinline__ int lowerb(const int* __restrict__ b, int n, int key) {
    int lo = 0, hi = n;
    while (lo < hi) {
        int mid = (lo + hi) >> 1;
        if (b[mid] < key) lo = mid + 1;
        else hi = mid;
    }
    return lo;
}

__global__ __launch_bounds__(256) void k_pool1(
    const ushort_t* __restrict__ h, const int* __restrict__ batch,
    float* __restrict__ ppart) {
    int g = blockIdx.x >> 4;
    int sl = blockIdx.x & (PSL - 1);
    int lo = lowerb(batch, NN, g);
    int hi = lowerb(batch, NN, g + 1);
    int cnt = hi - lo;
    int a = lo + (int)(((long long)cnt * sl) >> 4);
    int b = lo + (int)(((long long)cnt * (sl + 1)) >> 4);
    int wave = threadIdx.x >> 6, lane = threadIdx.x & 63;
    const ushort2* h2 = (const ushort2*)h;
    float ax = 0.f, ay = 0.f;
    for (int n = a + wave; n < b; n += 4) {
        ushort2 v = h2[(size_t)n * 64 + lane];
        ax += bf2f(v.x);
        ay += bf2f(v.y);
    }
    __shared__ float2 red[4][64];
    red[wave][lane] = make_float2(ax, ay);
    __syncthreads();
    if (wave == 0) {
        float sx = 0.f, sy = 0.f;
        for (int w = 0; w < 4; ++w) {
            sx += red[w][lane].x;
            sy += red[w][lane].y;
        }
        ((float2*)ppart)[(size_t)blockIdx.x * 64 + lane] = make_float2(sx, sy);
    }
}

// ---------------- Pooling, phase 2: combine slices + deferred BN affine ----------------

__global__ __launch_bounds__(64) void k_pool2(
    const float* __restrict__ ppart, const int* __restrict__ batch,
    const float* __restrict__ stats, const float* __restrict__ bng, const float* __restrict__ bnb,
    float* __restrict__ pooled) {
    int g = blockIdx.x;
    int lane = threadIdx.x;  // 0..63
    float sx = 0.f, sy = 0.f;
    #pragma unroll
    for (int s = 0; s < PSL; ++s) {
        float2 v = ((const float2*)ppart)[(size_t)(g * PSL + s) * 64 + lane];
        sx += v.x;
        sy += v.y;
    }
    int cnt = lowerb(batch, NN, g + 1) - lowerb(batch, NN, g);
    int c0 = lane * 2;
    const float inv_n = 1.0f / (float)NN;
    float m0 = stats[c0] * inv_n, m1 = stats[c0 + 1] * inv_n;
    float var0 = fmaf(-m0, m0, stats[HD + c0] * inv_n);
    float var1 = fmaf(-m1, m1, stats[HD + c0 + 1] * inv_n);
    float sc0 = bng[c0] * rsqrtf(var0 + 1e-5f);
    float sc1 = bng[c0 + 1] * rsqrtf(var1 + 1e-5f);
    float sh0 = bnb[c0] - m0 * sc0;
    float sh1 = bnb[c0 + 1] - m1 * sc1;
    float denom = fmaxf((float)cnt, 1.f);
    float2 o;
    o.x = (sc0 * sx + (float)cnt * sh0) / denom;
    o.y = (sc1 * sy + (float)cnt * sh1) / denom;
    ((float2*)pooled)[g * 64 + lane] = o;
}

// ---------------- MLP head + log_softmax (one wave per graph) ----------------

__global__ __launch_bounds__(64) void k_head(
    const float* __restrict__ pooled, const float* __restrict__ w1, const float* __restrict__ b1,
    const float* __restrict__ w2, const float* __restrict__ b2, float* __restrict__ out) {
    int g = blockIdx.x;
    int j = threadIdx.x;  // 0..63
    float hid = b1[j];
    const float* p = pooled + g * 128;
    #pragma unroll 8
    for (int k = 0; k < 128; ++k) hid = fmaf(p[k], w1[k * 64 + j], hid);
    float o[4];
    #pragma unroll
    for (int c = 0; c < 4; ++c) {
        float v = hid * w2[j * 4 + c];
        #pragma unroll
        for (int off = 1; off < 64; off <<= 1) v += __shfl_xor(v, off, 64);
        o[c] = v + b2[c];
    }
    if (j == 0) {
        float mx = fmaxf(fmaxf(o[0], o[1]), fmaxf(o[2], o[3]));
        float se = expf(o[0] - mx) + expf(o[1] - mx) + expf(o[2] - mx) + expf(o[3] - mx);
        float ls = mx + logf(se);
        #pragma unroll
        for (int c = 0; c < 4; ++c) out[g * 4 + c] = o[c] - ls;
    }
}

extern "C" void kernel_launch(void* const* d_in, const int* in_sizes, int n_in,
                              void* d_out, int out_size, void* d_ws, size_t ws_size,
                              hipStream_t stream) {
    const float* x = (const float*)d_in[0];
    const int* ei = (const int*)d_in[1];
    const int* batch = (const int*)d_in[2];
    const float* conv_w = (const float*)d_in[3];
    const float* conv_b = (const float*)d_in[4];
    const float* bn_g = (const float*)d_in[5];
    const float* bn_b = (const float*)d_in[6];
    const float* l1w = (const float*)d_in[7];
    const float* l1b = (const float*)d_in[8];
    const float* l2w = (const float*)d_in[9];
    const float* l2b = (const float*)d_in[10];
    float* out = (float*)d_out;
    (void)in_sizes; (void)n_in; (void)out_size; (void)ws_size;

    char* ws = (char*)d_ws;
    int* counts = (int*)(ws + 0);               // 400000 B
    int* cursor = (int*)(ws + 400000);          // 400000 B
    float* stats = (float*)(ws + 800000);       // 6*256 floats = 6144 B
    const size_t zero_bytes = 806144;           // counts + cursor + stats
    int* rowptr = (int*)(ws + 806144);          // 100001 ints
    int* bsums = (int*)(ws + 1206400);          // 391 ints
    int* colsrc = (int*)(ws + 1208192);         // 600000 ints -> ends 3608192
    float* pooled = (float*)(ws + 3608192);     // 64*128 floats -> ends 3640960
    float* ppart = (float*)(ws + 3641344);      // 1024*128 floats -> ends 4165632
    float* partials = (float*)(ws + 4165632);   // 1563*256 floats -> ends 5766144
    ushort_t* xb = (ushort_t*)(ws + 5766656);   // 25600000 B -> ends 31366656
    ushort_t* hb0 = (ushort_t*)(ws + 31366656); // 25600000 B -> ends 56966656
    ushort_t* hb1 = (ushort_t*)(ws + 56966656); // 25600000 B -> ends 82566656

    hipMemsetAsync(ws, 0, zero_bytes, stream);

    k_cast<<<(NN * 32 + 255) / 256, 256, 0, stream>>>(x, xb);

    int ebl = (NE + 255) / 256;
    int nb1 = (NN + 255) / 256;  // 391
    k_hist<<<ebl, 256, 0, stream>>>(ei, counts);
    k_scan1<<<nb1, 256, 0, stream>>>(counts, bsums);
    k_scan2<<<1, 512, 0, stream>>>(bsums, nb1);
    k_scan3<<<nb1, 256, 0, stream>>>(counts, bsums, rowptr);
    k_fill<<<ebl, 256, 0, stream>>>(ei, rowptr, cursor, colsrc);

    ushort_t* hb[2] = {hb0, hb1};
    for (int L = 0; L < NL; ++L) {
        const ushort_t* hin = (L == 0) ? xb : hb[(L + 1) & 1];
        ushort_t* hout = hb[L & 1];
        const float* lstats = (L == 0) ? nullptr : (stats + (L - 1) * 256);
        const float* lg = (L == 0) ? nullptr : (bn_g + (L - 1) * 128);
        const float* lb = (L == 0) ? nullptr : (bn_b + (L - 1) * 128);
        k_fused<<<NB, 256, 0, stream>>>(hin, rowptr, colsrc, lstats, lg, lb,
                                        conv_w + L * 16384, conv_b + L * 128,
                                        hout, partials);
        k_red<<<16, 256, 0, stream>>>(partials, stats + L * 256);
    }
    // final h is hb[5&1] = hb1
    k_pool1<<<NG * PSL, 256, 0, stream>>>(hb1, batch, ppart);
    k_pool2<<<NG, 64, 0, stream>>>(ppart, batch, stats + 5 * 256, bn_g + 5 * 128, bn_b + 5 * 128, pooled);
    k_head<<<NG, 64, 0, stream>>>(pooled, l1w, l1b, l2w, l2b, out);
}

// Round 8
// 910.543 us; speedup vs baseline: 1.3065x; 1.3065x over previous
//
#include <hip/hip_runtime.h>
#include <math.h>

#define NN 100000
#define NE 600000
#define NG 64
#define HD 128
#define NL 6
#define NB 1563   // conv blocks = ceil(NN/64)
#define PSL 16    // pool slices per graph

typedef unsigned short ushort_t;

__device__ __forceinline__ float bf2f(ushort_t u) {
    return __uint_as_float(((unsigned)u) << 16);
}
__device__ __forceinline__ ushort_t f2bf(float f) {
    unsigned u = __float_as_uint(f);
    unsigned r = (u + 0x7fffu + ((u >> 16) & 1u)) >> 16;   // round-to-nearest-even
    return (ushort_t)r;
}

// ---------------- x -> bf16 cast (once per call) ----------------

__global__ __launch_bounds__(256) void k_cast(const float* __restrict__ x,
                                              ushort_t* __restrict__ xb) {
    int i = blockIdx.x * 256 + threadIdx.x;   // one float4 -> ushort4 per thread
    if (i < NN * 32) {
        float4 v = ((const float4*)x)[i];
        ((ushort4*)xb)[i] = make_ushort4(f2bf(v.x), f2bf(v.y), f2bf(v.z), f2bf(v.w));
    }
}

// ---------------- CSR build ----------------

__global__ __launch_bounds__(256) void k_hist(const int* __restrict__ ei, int* __restrict__ counts) {
    int e = blockIdx.x * 256 + threadIdx.x;
    if (e < NE) atomicAdd(&counts[ei[NE + e]], 1);
}

__global__ __launch_bounds__(256) void k_scan1(const int* __restrict__ counts, int* __restrict__ bsums) {
    __shared__ int s[256];
    int i = blockIdx.x * 256 + threadIdx.x;
    s[threadIdx.x] = (i < NN) ? counts[i] : 0;
    __syncthreads();
    for (int off = 128; off > 0; off >>= 1) {
        if (threadIdx.x < off) s[threadIdx.x] += s[threadIdx.x + off];
        __syncthreads();
    }
    if (threadIdx.x == 0) bsums[blockIdx.x] = s[0];
}

__global__ __launch_bounds__(512) void k_scan2(int* __restrict__ bsums, int nb) {
    __shared__ int s[512];
    int t = threadIdx.x;
    s[t] = (t < nb) ? bsums[t] : 0;
    __syncthreads();
    for (int off = 1; off < 512; off <<= 1) {
        int v = (t >= off) ? s[t - off] : 0;
        __syncthreads();
        s[t] += v;
        __syncthreads();
    }
    if (t < nb) bsums[t] = (t == 0) ? 0 : s[t - 1];
}

__global__ __launch_bounds__(256) void k_scan3(const int* __restrict__ counts, const int* __restrict__ bsums,
                                               int* __restrict__ rowptr) {
    __shared__ int s[256];
    int t = threadIdx.x;
    int i = blockIdx.x * 256 + t;
    int v = (i < NN) ? counts[i] : 0;
    s[t] = v;
    __syncthreads();
    for (int off = 1; off < 256; off <<= 1) {
        int u = (t >= off) ? s[t - off] : 0;
        __syncthreads();
        s[t] += u;
        __syncthreads();
    }
    if (i < NN) rowptr[i] = bsums[blockIdx.x] + s[t] - v;
    if (i == 0) rowptr[NN] = NE;
}

__global__ __launch_bounds__(256) void k_fill(const int* __restrict__ ei, const int* __restrict__ rowptr,
                                              int* __restrict__ cursor, int* __restrict__ colsrc) {
    int e = blockIdx.x * 256 + threadIdx.x;
    if (e < NE) {
        int d = ei[NE + e];
        int pos = rowptr[d] + atomicAdd(&cursor[d], 1);
        colsrc[pos] = ei[e];
    }
}

// ---------------- Aggregation: 4 rows per wave, interleaved gather chains ----------
// Row bounds are wave-uniform -> predication is branch-free (cndmask on address +
// mask-multiply). 4 independent gather streams per wave ~ 4x bytes in flight vs the
// single-row version. Input bf16 h, output bf16 T (+ deferred BN affine).

__global__ __launch_bounds__(256) void k_agg(
    const ushort_t* __restrict__ hin, const int* __restrict__ rowptr,
    const int* __restrict__ colsrc, const float* __restrict__ stats,
    const float* __restrict__ bng, const float* __restrict__ bnb,
    ushort_t* __restrict__ tout) {
    int w = (blockIdx.x * 256 + threadIdx.x) >> 6;   // global wave id
    int lane = threadIdx.x & 63;
    int n0 = w * 4;
    if (n0 >= NN) return;

    int b[4], d[4];
    int prev = rowptr[n0];
    #pragma unroll
    for (int i = 0; i < 4; ++i) {
        int n = n0 + i;
        int nxt = (n < NN) ? rowptr[n + 1] : prev;
        b[i] = prev;
        d[i] = nxt - prev;
        prev = nxt;
    }
    int maxd = max(max(d[0], d[1]), max(d[2], d[3]));

    float acx[4] = {0.f, 0.f, 0.f, 0.f};
    float acy[4] = {0.f, 0.f, 0.f, 0.f};
    const ushort2* h2 = (const ushort2*)hin;
    for (int e = 0; e < maxd; ++e) {
        int idx[4];
        float msk[4];
        #pragma unroll
        for (int i = 0; i < 4; ++i) {
            bool v = e < d[i];
            idx[i] = v ? (b[i] + e) : 0;
            msk[i] = v ? 1.f : 0.f;
        }
        int s[4];
        #pragma unroll
        for (int i = 0; i < 4; ++i) s[i] = colsrc[idx[i]];
        ushort2 vv[4];
        #pragma unroll
        for (int i = 0; i < 4; ++i) vv[i] = h2[(size_t)s[i] * 64 + lane];
        #pragma unroll
        for (int i = 0; i < 4; ++i) {
            acx[i] = fmaf(msk[i], bf2f(vv[i].x), acx[i]);
            acy[i] = fmaf(msk[i], bf2f(vv[i].y), acy[i]);
        }
    }

    float sc0 = 1.f, sc1 = 1.f, sh0 = 0.f, sh1 = 0.f;
    if (stats != nullptr) {
        int c0 = lane * 2;
        const float inv_n = 1.0f / (float)NN;
        float m0 = stats[c0] * inv_n, m1 = stats[c0 + 1] * inv_n;
        float var0 = fmaf(-m0, m0, stats[HD + c0] * inv_n);
        float var1 = fmaf(-m1, m1, stats[HD + c0 + 1] * inv_n);
        sc0 = bng[c0] * rsqrtf(var0 + 1e-5f);
        sc1 = bng[c0 + 1] * rsqrtf(var1 + 1e-5f);
        sh0 = bnb[c0] - m0 * sc0;
        sh1 = bnb[c0 + 1] - m1 * sc1;
    }
    #pragma unroll
    for (int i = 0; i < 4; ++i) {
        int n = n0 + i;
        if (n < NN) {
            float degf = (float)d[i];
            float ox = fmaf(sc0, acx[i], degf * sh0);
            float oy = fmaf(sc1, acy[i], degf * sh1);
            ((ushort2*)tout)[(size_t)n * 64 + lane] = make_ushort2(f2bf(ox), f2bf(oy));
        }
    }
}

// ---------------- Conv GEMM: Hbf = bf16(relu(T @ W + b)), per-block BN partials ------
// T is bf16 (half the A-read traffic). At staged fp32 transposed (32 KB, XOR swizzle),
// Ws staged in 16 KB quarters -> 48 KB LDS -> 3 blocks/CU. Stats accumulated on the
// ROUNDED output values for self-consistency with downstream bf16 use.

__global__ __launch_bounds__(256) void k_conv(
    const ushort_t* __restrict__ T, const float* __restrict__ W,
    const float* __restrict__ bias, ushort_t* __restrict__ Hbf,
    float* __restrict__ partials) {
    __shared__ float At[128 * 64];   // [k][r^swz]  32 KB
    __shared__ float Ws[32 * 128];   // [kk][c]     16 KB
    int t = threadIdx.x;
    int row0 = blockIdx.x * 64;
    // stage 64 rows x 128 feats of bf16 T, transposed, XOR-swizzled
    const uint4* Tb = (const uint4*)T;   // 8 bf16 per uint4; row stride = 16 uint4
    #pragma unroll
    for (int it = 0; it < 4; ++it) {
        int id = t + 256 * it;
        int l = id & 63;
        int gn = id >> 6;                     // 0..15
        int r = 8 * (gn & 7) + (l >> 3);
        int k8i = 8 * (gn >> 3) + (l & 7);    // 0..15
        uint4 v = make_uint4(0u, 0u, 0u, 0u);
        int row = row0 + r;
        if (row < NN) v = Tb[(size_t)row * 16 + k8i];
        unsigned wds[4] = {v.x, v.y, v.z, v.w};
        int kb = 8 * k8i;
        #pragma unroll
        for (int p = 0; p < 4; ++p) {
            int k = kb + 2 * p;
            int rs = r ^ (8 * ((k >> 2) & 7));   // (k+1)>>2 == k>>2 (k even)
            At[k * 64 + rs] = bf2f((ushort_t)(wds[p] & 0xffffu));
            At[(k + 1) * 64 + rs] = bf2f((ushort_t)(wds[p] >> 16));
        }
    }

    int rg = t & 15, cg = t >> 4;
    int r0 = 4 * rg, c0 = 8 * cg;
    float acc[4][8];
    #pragma unroll
    for (int i = 0; i < 4; ++i)
        #pragma unroll
        for (int j = 0; j < 8; ++j) acc[i][j] = 0.f;

    #pragma unroll
    for (int q = 0; q < 4; ++q) {
        if (q) __syncthreads();
        const float4* Wq = (const float4*)(W + q * 32 * 128);
        #pragma unroll
        for (int it = 0; it < 4; ++it) {
            int id = t + 256 * it;
            ((float4*)Ws)[id] = Wq[id];
        }
        __syncthreads();  // q==0: also covers At staging
        #pragma unroll 4
        for (int kk = 0; kk < 32; ++kk) {
            int k = q * 32 + kk;
            float4 a = *(const float4*)&At[k * 64 + (r0 ^ (8 * ((k >> 2) & 7)))];
            const float4* wp = (const float4*)&Ws[kk * 128 + c0];
            float4 w0 = wp[0];
            float4 w1 = wp[1];
            float av[4] = {a.x, a.y, a.z, a.w};
            float wv[8] = {w0.x, w0.y, w0.z, w0.w, w1.x, w1.y, w1.z, w1.w};
            #pragma unroll
            for (int i = 0; i < 4; ++i)
                #pragma unroll
                for (int j = 0; j < 8; ++j) acc[i][j] = fmaf(av[i], wv[j], acc[i][j]);
        }
    }

    float bsv[8];
    #pragma unroll
    for (int j = 0; j < 8; ++j) bsv[j] = bias[c0 + j];
    float lsum[8], lsq[8];
    #pragma unroll
    for (int j = 0; j < 8; ++j) { lsum[j] = 0.f; lsq[j] = 0.f; }
    #pragma unroll
    for (int i = 0; i < 4; ++i) {
        int row = row0 + r0 + i;
        if (row < NN) {
            ushort_t hv[8];
            #pragma unroll
            for (int j = 0; j < 8; ++j) {
                float v = fmaxf(acc[i][j] + bsv[j], 0.f);
                ushort_t bb = f2bf(v);
                hv[j] = bb;
                float vr = bf2f(bb);
                lsum[j] += vr;
                lsq[j] = fmaf(vr, vr, lsq[j]);
            }
            ushort4* dst = (ushort4*)&Hbf[(size_t)row * 128 + c0];
            dst[0] = make_ushort4(hv[0], hv[1], hv[2], hv[3]);
            dst[1] = make_ushort4(hv[4], hv[5], hv[6], hv[7]);
        }
    }
    #pragma unroll
    for (int off = 1; off < 16; off <<= 1) {
        #pragma unroll
        for (int j = 0; j < 8; ++j) {
            lsum[j] += __shfl_xor(lsum[j], off, 64);
            lsq[j] += __shfl_xor(lsq[j], off, 64);
        }
    }
    if (rg == 0) {
        float* pr = partials + (size_t)blockIdx.x * 256;
        float4* p0 = (float4*)&pr[c0];
        p0[0] = make_float4(lsum[0], lsum[1], lsum[2], lsum[3]);
        p0[1] = make_float4(lsum[4], lsum[5], lsum[6], lsum[7]);
        float4* p1 = (float4*)&pr[HD + c0];
        p1[0] = make_float4(lsq[0], lsq[1], lsq[2], lsq[3]);
        p1[1] = make_float4(lsq[4], lsq[5], lsq[6], lsq[7]);
    }
}

// ---------------- Partial-stats reduction: 1563 x 256 -> 256 ----------------

__global__ __launch_bounds__(256) void k_red(const float* __restrict__ partials,
                                             float* __restrict__ stats) {
    int t = threadIdx.x;
    float s = 0.f;
    for (int r = blockIdx.x; r < NB; r += 16) s += partials[(size_t)r * 256 + t];
    atomicAdd(&stats[t], s);
}

// ---------------- Pooling, phase 1: per-(graph,slice) partial sums (bf16 h) ---------

__device__ __forceinline__ int lowerb(const int* __restrict__ b, int n, int key) {
    int lo = 0, hi = n;
    while (lo < hi) {
        int mid = (lo + hi) >> 1;
        if (b[mid] < key) lo = mid + 1;
        else hi = mid;
    }
    return lo;
}

__global__ __launch_bounds__(256) void k_pool1(
    const ushort_t* __restrict__ h, const int* __restrict__ batch,
    float* __restrict__ ppart) {
    int g = blockIdx.x >> 4;
    int sl = blockIdx.x & (PSL - 1);
    int lo = lowerb(batch, NN, g);
    int hi = lowerb(batch, NN, g + 1);
    int cnt = hi - lo;
    int a = lo + (int)(((long long)cnt * sl) >> 4);
    int b = lo + (int)(((long long)cnt * (sl + 1)) >> 4);
    int wave = threadIdx.x >> 6, lane = threadIdx.x & 63;
    const ushort2* h2 = (const ushort2*)h;
    float ax = 0.f, ay = 0.f;
    for (int n = a + wave; n < b; n += 4) {
        ushort2 v = h2[(size_t)n * 64 + lane];
        ax += bf2f(v.x);
        ay += bf2f(v.y);
    }
    __shared__ float2 red[4][64];
    red[wave][lane] = make_float2(ax, ay);
    __syncthreads();
    if (wave == 0) {
        float sx = 0.f, sy = 0.f;
        for (int w = 0; w < 4; ++w) {
            sx += red[w][lane].x;
            sy += red[w][lane].y;
        }
        ((float2*)ppart)[(size_t)blockIdx.x * 64 + lane] = make_float2(sx, sy);
    }
}

// ---------------- Pooling, phase 2: combine slices + deferred BN affine ----------------

__global__ __launch_bounds__(64) void k_pool2(
    const float* __restrict__ ppart, const int* __restrict__ batch,
    const float* __restrict__ stats, const float* __restrict__ bng, const float* __restrict__ bnb,
    float* __restrict__ pooled) {
    int g = blockIdx.x;
    int lane = threadIdx.x;  // 0..63
    float sx = 0.f, sy = 0.f;
    #pragma unroll
    for (int s = 0; s < PSL; ++s) {
        float2 v = ((const float2*)ppart)[(size_t)(g * PSL + s) * 64 + lane];
        sx += v.x;
        sy += v.y;
    }
    int cnt = lowerb(batch, NN, g + 1) - lowerb(batch, NN, g);
    int c0 = lane * 2;
    const float inv_n = 1.0f / (float)NN;
    float m0 = stats[c0] * inv_n, m1 = stats[c0 + 1] * inv_n;
    float var0 = fmaf(-m0, m0, stats[HD + c0] * inv_n);
    float var1 = fmaf(-m1, m1, stats[HD + c0 + 1] * inv_n);
    float sc0 = bng[c0] * rsqrtf(var0 + 1e-5f);
    float sc1 = bng[c0 + 1] * rsqrtf(var1 + 1e-5f);
    float sh0 = bnb[c0] - m0 * sc0;
    float sh1 = bnb[c0 + 1] - m1 * sc1;
    float denom = fmaxf((float)cnt, 1.f);
    float2 o;
    o.x = (sc0 * sx + (float)cnt * sh0) / denom;
    o.y = (sc1 * sy + (float)cnt * sh1) / denom;
    ((float2*)pooled)[g * 64 + lane] = o;
}

// ---------------- MLP head + log_softmax (one wave per graph) ----------------

__global__ __launch_bounds__(64) void k_head(
    const float* __restrict__ pooled, const float* __restrict__ w1, const float* __restrict__ b1,
    const float* __restrict__ w2, const float* __restrict__ b2, float* __restrict__ out) {
    int g = blockIdx.x;
    int j = threadIdx.x;  // 0..63
    float hid = b1[j];
    const float* p = pooled + g * 128;
    #pragma unroll 8
    for (int k = 0; k < 128; ++k) hid = fmaf(p[k], w1[k * 64 + j], hid);
    float o[4];
    #pragma unroll
    for (int c = 0; c < 4; ++c) {
        float v = hid * w2[j * 4 + c];
        #pragma unroll
        for (int off = 1; off < 64; off <<= 1) v += __shfl_xor(v, off, 64);
        o[c] = v + b2[c];
    }
    if (j == 0) {
        float mx = fmaxf(fmaxf(o[0], o[1]), fmaxf(o[2], o[3]));
        float se = expf(o[0] - mx) + expf(o[1] - mx) + expf(o[2] - mx) + expf(o[3] - mx);
        float ls = mx + logf(se);
        #pragma unroll
        for (int c = 0; c < 4; ++c) out[g * 4 + c] = o[c] - ls;
    }
}

extern "C" void kernel_launch(void* const* d_in, const int* in_sizes, int n_in,
                              void* d_out, int out_size, void* d_ws, size_t ws_size,
                              hipStream_t stream) {
    const float* x = (const float*)d_in[0];
    const int* ei = (const int*)d_in[1];
    const int* batch = (const int*)d_in[2];
    const float* conv_w = (const float*)d_in[3];
    const float* conv_b = (const float*)d_in[4];
    const float* bn_g = (const float*)d_in[5];
    const float* bn_b = (const float*)d_in[6];
    const float* l1w = (const float*)d_in[7];
    const float* l1b = (const float*)d_in[8];
    const float* l2w = (const float*)d_in[9];
    const float* l2b = (const float*)d_in[10];
    float* out = (float*)d_out;
    (void)in_sizes; (void)n_in; (void)out_size; (void)ws_size;

    char* ws = (char*)d_ws;
    int* counts = (int*)(ws + 0);               // 400000 B
    int* cursor = (int*)(ws + 400000);          // 400000 B
    float* stats = (float*)(ws + 800000);       // 6*256 floats = 6144 B
    const size_t zero_bytes = 806144;           // counts + cursor + stats
    int* rowptr = (int*)(ws + 806144);          // 100001 ints
    int* bsums = (int*)(ws + 1206400);          // 391 ints
    int* colsrc = (int*)(ws + 1208192);         // 600000 ints -> ends 3608192
    float* pooled = (float*)(ws + 3608192);     // 64*128 floats -> ends 3640960
    float* ppart = (float*)(ws + 3641344);      // 1024*128 floats -> ends 4165632
    float* partials = (float*)(ws + 4165632);   // 1563*256 floats -> ends 5766144
    ushort_t* xb = (ushort_t*)(ws + 5766656);   // 25600000 B -> ends 31366656
    ushort_t* tbuf = (ushort_t*)(ws + 31366656);// 25600000 B bf16 T -> ends 56966656
    ushort_t* hbuf = (ushort_t*)(ws + 56966656);// 25600000 B bf16 h -> ends 82566656

    hipMemsetAsync(ws, 0, zero_bytes, stream);

    k_cast<<<(NN * 32 + 255) / 256, 256, 0, stream>>>(x, xb);

    int ebl = (NE + 255) / 256;
    int nb1 = (NN + 255) / 256;  // 391
    k_hist<<<ebl, 256, 0, stream>>>(ei, counts);
    k_scan1<<<nb1, 256, 0, stream>>>(counts, bsums);
    k_scan2<<<1, 512, 0, stream>>>(bsums, nb1);
    k_scan3<<<nb1, 256, 0, stream>>>(counts, bsums, rowptr);
    k_fill<<<ebl, 256, 0, stream>>>(ei, rowptr, cursor, colsrc);

    // 4 rows per wave, 16 rows per block -> 6250 blocks
    const int agg_blocks = (NN + 15) / 16;
    for (int L = 0; L < NL; ++L) {
        const ushort_t* hin = (L == 0) ? xb : hbuf;
        const float* lstats = (L == 0) ? nullptr : (stats + (L - 1) * 256);
        const float* lg = (L == 0) ? nullptr : (bn_g + (L - 1) * 128);
        const float* lb = (L == 0) ? nullptr : (bn_b + (L - 1) * 128);
        k_agg<<<agg_blocks, 256, 0, stream>>>(hin, rowptr, colsrc, lstats, lg, lb, tbuf);
        k_conv<<<NB, 256, 0, stream>>>(tbuf, conv_w + L * 16384, conv_b + L * 128,
                                       hbuf, partials);
        k_red<<<16, 256, 0, stream>>>(partials, stats + L * 256);
    }
    k_pool1<<<NG * PSL, 256, 0, stream>>>(hbuf, batch, ppart);
    k_pool2<<<NG, 64, 0, stream>>>(ppart, batch, stats + 5 * 256, bn_g + 5 * 128, bn_b + 5 * 128, pooled);
    k_head<<<NG, 64, 0, stream>>>(pooled, l1w, l1b, l2w, l2b, out);
}

// Round 9
// 882.193 us; speedup vs baseline: 1.3485x; 1.0321x over previous
//
#include <hip/hip_runtime.h>
#include <math.h>

#define NN 100000
#define NE 600000
#define NG 64
#define HD 128
#define NL 6
#define NB 1563   // conv blocks = ceil(NN/64)
#define PSL 16    // pool slices per graph

typedef unsigned short ushort_t;
typedef short short8 __attribute__((ext_vector_type(8)));
typedef float floatx4 __attribute__((ext_vector_type(4)));

__device__ __forceinline__ float bf2f(ushort_t u) {
    return __uint_as_float(((unsigned)u) << 16);
}
__device__ __forceinline__ ushort_t f2bf(float f) {
    unsigned u = __float_as_uint(f);
    unsigned r = (u + 0x7fffu + ((u >> 16) & 1u)) >> 16;   // round-to-nearest-even
    return (ushort_t)r;
}

// ---------------- x -> bf16 cast (once per call) ----------------

__global__ __launch_bounds__(256) void k_cast(const float* __restrict__ x,
                                              ushort_t* __restrict__ xb) {
    int i = blockIdx.x * 256 + threadIdx.x;   // one float4 -> ushort4 per thread
    if (i < NN * 32) {
        float4 v = ((const float4*)x)[i];
        ((ushort4*)xb)[i] = make_ushort4(f2bf(v.x), f2bf(v.y), f2bf(v.z), f2bf(v.w));
    }
}

// ---------------- W -> bf16 transpose: Wt[L][col][k] (once per call, 6 blocks) ------

__global__ __launch_bounds__(256) void k_wcast(const float* __restrict__ W,
                                               ushort_t* __restrict__ Wt) {
    const float* Wl = W + blockIdx.x * 16384;
    ushort_t* Wtl = Wt + blockIdx.x * 16384;
    for (int id = threadIdx.x; id < 16384; id += 256) {
        int k = id >> 7, c = id & 127;
        Wtl[c * 128 + k] = f2bf(Wl[id]);
    }
}

// ---------------- CSR build ----------------

__global__ __launch_bounds__(256) void k_hist(const int* __restrict__ ei, int* __restrict__ counts) {
    int e = blockIdx.x * 256 + threadIdx.x;
    if (e < NE) atomicAdd(&counts[ei[NE + e]], 1);
}

__global__ __launch_bounds__(256) void k_scan1(const int* __restrict__ counts, int* __restrict__ bsums) {
    __shared__ int s[256];
    int i = blockIdx.x * 256 + threadIdx.x;
    s[threadIdx.x] = (i < NN) ? counts[i] : 0;
    __syncthreads();
    for (int off = 128; off > 0; off >>= 1) {
        if (threadIdx.x < off) s[threadIdx.x] += s[threadIdx.x + off];
        __syncthreads();
    }
    if (threadIdx.x == 0) bsums[blockIdx.x] = s[0];
}

__global__ __launch_bounds__(512) void k_scan2(int* __restrict__ bsums, int nb) {
    __shared__ int s[512];
    int t = threadIdx.x;
    s[t] = (t < nb) ? bsums[t] : 0;
    __syncthreads();
    for (int off = 1; off < 512; off <<= 1) {
        int v = (t >= off) ? s[t - off] : 0;
        __syncthreads();
        s[t] += v;
        __syncthreads();
    }
    if (t < nb) bsums[t] = (t == 0) ? 0 : s[t - 1];
}

__global__ __launch_bounds__(256) void k_scan3(const int* __restrict__ counts, const int* __restrict__ bsums,
                                               int* __restrict__ rowptr) {
    __shared__ int s[256];
    int t = threadIdx.x;
    int i = blockIdx.x * 256 + t;
    int v = (i < NN) ? counts[i] : 0;
    s[t] = v;
    __syncthreads();
    for (int off = 1; off < 256; off <<= 1) {
        int u = (t >= off) ? s[t - off] : 0;
        __syncthreads();
        s[t] += u;
        __syncthreads();
    }
    if (i < NN) rowptr[i] = bsums[blockIdx.x] + s[t] - v;
    if (i == 0) rowptr[NN] = NE;
}

__global__ __launch_bounds__(256) void k_fill(const int* __restrict__ ei, const int* __restrict__ rowptr,
                                              int* __restrict__ cursor, int* __restrict__ colsrc) {
    int e = blockIdx.x * 256 + threadIdx.x;
    if (e < NE) {
        int d = ei[NE + e];
        int pos = rowptr[d] + atomicAdd(&cursor[d], 1);
        colsrc[pos] = ei[e];
    }
}

// ---------------- Aggregation: 4 rows per wave, interleaved gather chains ----------

__global__ __launch_bounds__(256) void k_agg(
    const ushort_t* __restrict__ hin, const int* __restrict__ rowptr,
    const int* __restrict__ colsrc, const float* __restrict__ stats,
    const float* __restrict__ bng, const float* __restrict__ bnb,
    ushort_t* __restrict__ tout) {
    int w = (blockIdx.x * 256 + threadIdx.x) >> 6;   // global wave id
    int lane = threadIdx.x & 63;
    int n0 = w * 4;
    if (n0 >= NN) return;

    int b[4], d[4];
    int prev = rowptr[n0];
    #pragma unroll
    for (int i = 0; i < 4; ++i) {
        int n = n0 + i;
        int nxt = (n < NN) ? rowptr[n + 1] : prev;
        b[i] = prev;
        d[i] = nxt - prev;
        prev = nxt;
    }
    int maxd = max(max(d[0], d[1]), max(d[2], d[3]));

    float acx[4] = {0.f, 0.f, 0.f, 0.f};
    float acy[4] = {0.f, 0.f, 0.f, 0.f};
    const ushort2* h2 = (const ushort2*)hin;
    for (int e = 0; e < maxd; ++e) {
        int idx[4];
        float msk[4];
        #pragma unroll
        for (int i = 0; i < 4; ++i) {
            bool v = e < d[i];
            idx[i] = v ? (b[i] + e) : 0;
            msk[i] = v ? 1.f : 0.f;
        }
        int s[4];
        #pragma unroll
        for (int i = 0; i < 4; ++i) s[i] = colsrc[idx[i]];
        ushort2 vv[4];
        #pragma unroll
        for (int i = 0; i < 4; ++i) vv[i] = h2[(size_t)s[i] * 64 + lane];
        #pragma unroll
        for (int i = 0; i < 4; ++i) {
            acx[i] = fmaf(msk[i], bf2f(vv[i].x), acx[i]);
            acy[i] = fmaf(msk[i], bf2f(vv[i].y), acy[i]);
        }
    }

    float sc0 = 1.f, sc1 = 1.f, sh0 = 0.f, sh1 = 0.f;
    if (stats != nullptr) {
        int c0 = lane * 2;
        const float inv_n = 1.0f / (float)NN;
        float m0 = stats[c0] * inv_n, m1 = stats[c0 + 1] * inv_n;
        float var0 = fmaf(-m0, m0, stats[HD + c0] * inv_n);
        float var1 = fmaf(-m1, m1, stats[HD + c0 + 1] * inv_n);
        sc0 = bng[c0] * rsqrtf(var0 + 1e-5f);
        sc1 = bng[c0 + 1] * rsqrtf(var1 + 1e-5f);
        sh0 = bnb[c0] - m0 * sc0;
        sh1 = bnb[c0 + 1] - m1 * sc1;
    }
    #pragma unroll
    for (int i = 0; i < 4; ++i) {
        int n = n0 + i;
        if (n < NN) {
            float degf = (float)d[i];
            float ox = fmaf(sc0, acx[i], degf * sh0);
            float oy = fmaf(sc1, acy[i], degf * sh1);
            ((ushort2*)tout)[(size_t)n * 64 + lane] = make_ushort2(f2bf(ox), f2bf(oy));
        }
    }
}

// ---------------- Conv GEMM via MFMA: Hbf = bf16(relu(T @ W + b)) ----------------
// 64 rows/block, 4 waves x 16 rows. A-frags straight from global bf16 T
// (A[m=lane&15][k=quad*8+j], 16-B loads). B-frags from Wt[col][k] bf16
// (B[k][n=lane&15], 16-B loads, L1-resident 32 KB). 32 MFMA/wave, fp32 accum.
// D layout: col=lane&15, row=quad*4+reg. Stats: shfl over lane bits 4,5 then
// LDS atomics; partials written per block (no contended global atomics).

__global__ __launch_bounds__(256) void k_conv(
    const ushort_t* __restrict__ T, const ushort_t* __restrict__ Wt,
    const float* __restrict__ bias, ushort_t* __restrict__ Hbf,
    float* __restrict__ partials) {
    __shared__ float sstat[256];
    int t = threadIdx.x;
    sstat[t] = 0.f;
    __syncthreads();
    int wave = t >> 6, lane = t & 63;
    int l15 = lane & 15, quad = lane >> 4;
    int rowbase = blockIdx.x * 64 + wave * 16;

    int arow = rowbase + l15;
    bool avalid = arow < NN;
    short8 afrag[4];
    size_t aoff = (size_t)arow * 128 + quad * 8;   // ushort index
    #pragma unroll
    for (int s = 0; s < 4; ++s) {
        short8 v = {0, 0, 0, 0, 0, 0, 0, 0};
        if (avalid) v = *(const short8*)(T + aoff + 32 * s);
        afrag[s] = v;
    }

    floatx4 acc[8];
    #pragma unroll
    for (int c = 0; c < 8; ++c) acc[c] = (floatx4){0.f, 0.f, 0.f, 0.f};

    #pragma unroll
    for (int c = 0; c < 8; ++c) {
        size_t boff = (size_t)(16 * c + l15) * 128 + quad * 8;
        #pragma unroll
        for (int s = 0; s < 4; ++s) {
            short8 bf = *(const short8*)(Wt + boff + 32 * s);
            acc[c] = __builtin_amdgcn_mfma_f32_16x16x32_bf16(afrag[s], bf, acc[c], 0, 0, 0);
        }
    }

    int orow0 = rowbase + quad * 4;
    #pragma unroll
    for (int c = 0; c < 8; ++c) {
        int col = 16 * c + l15;
        float bv = bias[col];
        float ls = 0.f, lq = 0.f;
        #pragma unroll
        for (int i = 0; i < 4; ++i) {
            int row = orow0 + i;
            if (row < NN) {
                float v = fmaxf(acc[c][i] + bv, 0.f);
                ushort_t bb = f2bf(v);
                Hbf[(size_t)row * 128 + col] = bb;
                float vr = bf2f(bb);
                ls += vr;
                lq = fmaf(vr, vr, lq);
            }
        }
        ls += __shfl_xor(ls, 16, 64);
        ls += __shfl_xor(ls, 32, 64);
        lq += __shfl_xor(lq, 16, 64);
        lq += __shfl_xor(lq, 32, 64);
        if (quad == 0) {
            atomicAdd(&sstat[col], ls);
            atomicAdd(&sstat[128 + col], lq);
        }
    }
    __syncthreads();
    partials[(size_t)blockIdx.x * 256 + t] = sstat[t];
}

// ---------------- Partial-stats reduction: 1563 x 256 -> 256 ----------------

__global__ __launch_bounds__(256) void k_red(const float* __restrict__ partials,
                                             float* __restrict__ stats) {
    int t = threadIdx.x;
    float s = 0.f;
    for (int r = blockIdx.x; r < NB; r += 16) s += partials[(size_t)r * 256 + t];
    atomicAdd(&stats[t], s);
}

// ---------------- Pooling, phase 1: per-(graph,slice) partial sums (bf16 h) ---------

__device__ __forceinline__ int lowerb(const int* __restrict__ b, int n, int key) {
    int lo = 0, hi = n;
    while (lo < hi) {
        int mid = (lo + hi) >> 1;
        if (b[mid] < key) lo = mid + 1;
        else hi = mid;
    }
    return lo;
}

__global__ __launch_bounds__(256) void k_pool1(
    const ushort_t* __restrict__ h, const int* __restrict__ batch,
    float* __restrict__ ppart) {
    int g = blockIdx.x >> 4;
    int sl = blockIdx.x & (PSL - 1);
    int lo = lowerb(batch, NN, g);
    int hi = lowerb(batch, NN, g + 1);
    int cnt = hi - lo;
    int a = lo + (int)(((long long)cnt * sl) >> 4);
    int b = lo + (int)(((long long)cnt * (sl + 1)) >> 4);
    int wave = threadIdx.x >> 6, lane = threadIdx.x & 63;
    const ushort2* h2 = (const ushort2*)h;
    float ax = 0.f, ay = 0.f;
    for (int n = a + wave; n < b; n += 4) {
        ushort2 v = h2[(size_t)n * 64 + lane];
        ax += bf2f(v.x);
        ay += bf2f(v.y);
    }
    __shared__ float2 red[4][64];
    red[wave][lane] = make_float2(ax, ay);
    __syncthreads();
    if (wave == 0) {
        float sx = 0.f, sy = 0.f;
        for (int w = 0; w < 4; ++w) {
            sx += red[w][lane].x;
            sy += red[w][lane].y;
        }
        ((float2*)ppart)[(size_t)blockIdx.x * 64 + lane] = make_float2(sx, sy);
    }
}

// ---------------- Pooling, phase 2: combine slices + deferred BN affine ----------------

__global__ __launch_bounds__(64) void k_pool2(
    const float* __restrict__ ppart, const int* __restrict__ batch,
    const float* __restrict__ stats, const float* __restrict__ bng, const float* __restrict__ bnb,
    float* __restrict__ pooled) {
    int g = blockIdx.x;
    int lane = threadIdx.x;  // 0..63
    float sx = 0.f, sy = 0.f;
    #pragma unroll
    for (int s = 0; s < PSL; ++s) {
        float2 v = ((const float2*)ppart)[(size_t)(g * PSL + s) * 64 + lane];
        sx += v.x;
        sy += v.y;
    }
    int cnt = lowerb(batch, NN, g + 1) - lowerb(batch, NN, g);
    int c0 = lane * 2;
    const float inv_n = 1.0f / (float)NN;
    float m0 = stats[c0] * inv_n, m1 = stats[c0 + 1] * inv_n;
    float var0 = fmaf(-m0, m0, stats[HD + c0] * inv_n);
    float var1 = fmaf(-m1, m1, stats[HD + c0 + 1] * inv_n);
    float sc0 = bng[c0] * rsqrtf(var0 + 1e-5f);
    float sc1 = bng[c0 + 1] * rsqrtf(var1 + 1e-5f);
    float sh0 = bnb[c0] - m0 * sc0;
    float sh1 = bnb[c0 + 1] - m1 * sc1;
    float denom = fmaxf((float)cnt, 1.f);
    float2 o;
    o.x = (sc0 * sx + (float)cnt * sh0) / denom;
    o.y = (sc1 * sy + (float)cnt * sh1) / denom;
    ((float2*)pooled)[g * 64 + lane] = o;
}

// ---------------- MLP head + log_softmax (one wave per graph) ----------------

__global__ __launch_bounds__(64) void k_head(
    const float* __restrict__ pooled, const float* __restrict__ w1, const float* __restrict__ b1,
    const float* __restrict__ w2, const float* __restrict__ b2, float* __restrict__ out) {
    int g = blockIdx.x;
    int j = threadIdx.x;  // 0..63
    float hid = b1[j];
    const float* p = pooled + g * 128;
    #pragma unroll 8
    for (int k = 0; k < 128; ++k) hid = fmaf(p[k], w1[k * 64 + j], hid);
    float o[4];
    #pragma unroll
    for (int c = 0; c < 4; ++c) {
        float v = hid * w2[j * 4 + c];
        #pragma unroll
        for (int off = 1; off < 64; off <<= 1) v += __shfl_xor(v, off, 64);
        o[c] = v + b2[c];
    }
    if (j == 0) {
        float mx = fmaxf(fmaxf(o[0], o[1]), fmaxf(o[2], o[3]));
        float se = expf(o[0] - mx) + expf(o[1] - mx) + expf(o[2] - mx) + expf(o[3] - mx);
        float ls = mx + logf(se);
        #pragma unroll
        for (int c = 0; c < 4; ++c) out[g * 4 + c] = o[c] - ls;
    }
}

extern "C" void kernel_launch(void* const* d_in, const int* in_sizes, int n_in,
                              void* d_out, int out_size, void* d_ws, size_t ws_size,
                              hipStream_t stream) {
    const float* x = (const float*)d_in[0];
    const int* ei = (const int*)d_in[1];
    const int* batch = (const int*)d_in[2];
    const float* conv_w = (const float*)d_in[3];
    const float* conv_b = (const float*)d_in[4];
    const float* bn_g = (const float*)d_in[5];
    const float* bn_b = (const float*)d_in[6];
    const float* l1w = (const float*)d_in[7];
    const float* l1b = (const float*)d_in[8];
    const float* l2w = (const float*)d_in[9];
    const float* l2b = (const float*)d_in[10];
    float* out = (float*)d_out;
    (void)in_sizes; (void)n_in; (void)out_size; (void)ws_size;

    char* ws = (char*)d_ws;
    int* counts = (int*)(ws + 0);               // 400000 B
    int* cursor = (int*)(ws + 400000);          // 400000 B
    float* stats = (float*)(ws + 800000);       // 6*256 floats = 6144 B
    const size_t zero_bytes = 806144;           // counts + cursor + stats
    int* rowptr = (int*)(ws + 806144);          // 100001 ints
    int* bsums = (int*)(ws + 1206400);          // 391 ints
    int* colsrc = (int*)(ws + 1208192);         // 600000 ints -> ends 3608192
    float* pooled = (float*)(ws + 3608192);     // 64*128 floats -> ends 3640960
    float* ppart = (float*)(ws + 3641344);      // 1024*128 floats -> ends 4165632
    float* partials = (float*)(ws + 4165632);   // 1563*256 floats -> ends 5766144
    ushort_t* xb = (ushort_t*)(ws + 5766656);   // 25600000 B -> ends 31366656
    ushort_t* tbuf = (ushort_t*)(ws + 31366656);// 25600000 B bf16 T -> ends 56966656
    ushort_t* hbuf = (ushort_t*)(ws + 56966656);// 25600000 B bf16 h -> ends 82566656
    ushort_t* wtbuf = (ushort_t*)(ws + 82566656);// 6*16384*2 B = 196608 -> ends 82763264

    hipMemsetAsync(ws, 0, zero_bytes, stream);

    k_cast<<<(NN * 32 + 255) / 256, 256, 0, stream>>>(x, xb);
    k_wcast<<<NL, 256, 0, stream>>>(conv_w, wtbuf);

    int ebl = (NE + 255) / 256;
    int nb1 = (NN + 255) / 256;  // 391
    k_hist<<<ebl, 256, 0, stream>>>(ei, counts);
    k_scan1<<<nb1, 256, 0, stream>>>(counts, bsums);
    k_scan2<<<1, 512, 0, stream>>>(bsums, nb1);
    k_scan3<<<nb1, 256, 0, stream>>>(counts, bsums, rowptr);
    k_fill<<<ebl, 256, 0, stream>>>(ei, rowptr, cursor, colsrc);

    // 4 rows per wave, 16 rows per block -> 6250 blocks
    const int agg_blocks = (NN + 15) / 16;
    for (int L = 0; L < NL; ++L) {
        const ushort_t* hin = (L == 0) ? xb : hbuf;
        const float* lstats = (L == 0) ? nullptr : (stats + (L - 1) * 256);
        const float* lg = (L == 0) ? nullptr : (bn_g + (L - 1) * 128);
        const float* lb = (L == 0) ? nullptr : (bn_b + (L - 1) * 128);
        k_agg<<<agg_blocks, 256, 0, stream>>>(hin, rowptr, colsrc, lstats, lg, lb, tbuf);
        k_conv<<<NB, 256, 0, stream>>>(tbuf, wtbuf + L * 16384, conv_b + L * 128,
                                       hbuf, partials);
        k_red<<<16, 256, 0, stream>>>(partials, stats + L * 256);
    }
    k_pool1<<<NG * PSL, 256, 0, stream>>>(hbuf, batch, ppart);
    k_pool2<<<NG, 64, 0, stream>>>(ppart, batch, stats + 5 * 256, bn_g + 5 * 128, bn_b + 5 * 128, pooled);
    k_head<<<NG, 64, 0, stream>>>(pooled, l1w, l1b, l2w, l2b, out);
}

// Round 10
// 786.073 us; speedup vs baseline: 1.5134x; 1.1223x over previous
//
#include <hip/hip_runtime.h>
#include <math.h>

#define NN 100000
#define NE 600000
#define NG 64
#define HD 128
#define NL 6
#define NB 1563   // gconv blocks = ceil(NN/64)
#define PSL 16    // pool slices per graph

typedef unsigned short ushort_t;
typedef short short8 __attribute__((ext_vector_type(8)));
typedef float floatx4 __attribute__((ext_vector_type(4)));

__device__ __forceinline__ float bf2f(ushort_t u) {
    return __uint_as_float(((unsigned)u) << 16);
}
__device__ __forceinline__ ushort_t f2bf(float f) {
    unsigned u = __float_as_uint(f);
    unsigned r = (u + 0x7fffu + ((u >> 16) & 1u)) >> 16;   // round-to-nearest-even
    return (ushort_t)r;
}

// ---------------- x -> bf16 cast (once per call) ----------------

__global__ __launch_bounds__(256) void k_cast(const float* __restrict__ x,
                                              ushort_t* __restrict__ xb) {
    int i = blockIdx.x * 256 + threadIdx.x;
    if (i < NN * 32) {
        float4 v = ((const float4*)x)[i];
        ((ushort4*)xb)[i] = make_ushort4(f2bf(v.x), f2bf(v.y), f2bf(v.z), f2bf(v.w));
    }
}

// ---------------- W -> bf16 transpose: Wt[L][col][k] ----------------

__global__ __launch_bounds__(256) void k_wcast(const float* __restrict__ W,
                                               ushort_t* __restrict__ Wt) {
    const float* Wl = W + blockIdx.x * 16384;
    ushort_t* Wtl = Wt + blockIdx.x * 16384;
    for (int id = threadIdx.x; id < 16384; id += 256) {
        int k = id >> 7, c = id & 127;
        Wtl[c * 128 + k] = f2bf(Wl[id]);
    }
}

// ---------------- CSR build ----------------

__global__ __launch_bounds__(256) void k_hist(const int* __restrict__ ei, int* __restrict__ counts) {
    int e = blockIdx.x * 256 + threadIdx.x;
    if (e < NE) atomicAdd(&counts[ei[NE + e]], 1);
}

__global__ __launch_bounds__(256) void k_scan1(const int* __restrict__ counts, int* __restrict__ bsums) {
    __shared__ int s[256];
    int i = blockIdx.x * 256 + threadIdx.x;
    s[threadIdx.x] = (i < NN) ? counts[i] : 0;
    __syncthreads();
    for (int off = 128; off > 0; off >>= 1) {
        if (threadIdx.x < off) s[threadIdx.x] += s[threadIdx.x + off];
        __syncthreads();
    }
    if (threadIdx.x == 0) bsums[blockIdx.x] = s[0];
}

__global__ __launch_bounds__(512) void k_scan2(int* __restrict__ bsums, int nb) {
    __shared__ int s[512];
    int t = threadIdx.x;
    s[t] = (t < nb) ? bsums[t] : 0;
    __syncthreads();
    for (int off = 1; off < 512; off <<= 1) {
        int v = (t >= off) ? s[t - off] : 0;
        __syncthreads();
        s[t] += v;
        __syncthreads();
    }
    if (t < nb) bsums[t] = (t == 0) ? 0 : s[t - 1];
}

__global__ __launch_bounds__(256) void k_scan3(const int* __restrict__ counts, const int* __restrict__ bsums,
                                               int* __restrict__ rowptr) {
    __shared__ int s[256];
    int t = threadIdx.x;
    int i = blockIdx.x * 256 + t;
    int v = (i < NN) ? counts[i] : 0;
    s[t] = v;
    __syncthreads();
    for (int off = 1; off < 256; off <<= 1) {
        int u = (t >= off) ? s[t - off] : 0;
        __syncthreads();
        s[t] += u;
        __syncthreads();
    }
    if (i < NN) rowptr[i] = bsums[blockIdx.x] + s[t] - v;
    if (i == 0) rowptr[NN] = NE;
}

__global__ __launch_bounds__(256) void k_fill(const int* __restrict__ ei, const int* __restrict__ rowptr,
                                              int* __restrict__ cursor, int* __restrict__ colsrc) {
    int e = blockIdx.x * 256 + threadIdx.x;
    if (e < NE) {
        int d = ei[NE + e];
        int pos = rowptr[d] + atomicAdd(&cursor[d], 1);
        colsrc[pos] = ei[e];
    }
}

// ---------------- Fused gather->MFMA layer kernel ----------------
// 64 rows/block, 4 waves x 16 rows. Gather happens DIRECTLY in A-fragment layout:
// lane (l15,quad) accumulates row (base+l15), features {s*32+quad*8+j} in fp32,
// 4 independent 16-B loads per edge-step, 2-way edge unroll (8 loads in flight).
// BN affine applied in fp32, packed to bf16 afrag (numerically == R9 path).
// Then the verified R9 MFMA phase: B from Wt[col][k], D col=lane&15 row=quad*4+reg.
// No LDS tile, no tbuf round-trip (saves 51 MB/layer), no cross-wave barrier
// until the stats epilogue.

__global__ __launch_bounds__(256) void k_gconv(
    const ushort_t* __restrict__ hin,
    const int* __restrict__ rowptr, const int* __restrict__ colsrc,
    const float* __restrict__ stats, const float* __restrict__ bng,
    const float* __restrict__ bnb,
    const ushort_t* __restrict__ Wt, const float* __restrict__ bias,
    ushort_t* __restrict__ hout, float* __restrict__ partials) {
    __shared__ float sstat[256];
    int t = threadIdx.x;
    sstat[t] = 0.f;
    int wave = t >> 6, lane = t & 63;
    int l15 = lane & 15, quad = lane >> 4;
    int rowbase = blockIdx.x * 64 + wave * 16;
    int row = rowbase + l15;
    bool valid = row < NN;
    int beg = valid ? rowptr[row] : 0;
    int end = valid ? rowptr[row + 1] : 0;
    int deg = end - beg;
    int maxd = deg;
    maxd = max(maxd, __shfl_xor(maxd, 1, 64));
    maxd = max(maxd, __shfl_xor(maxd, 2, 64));
    maxd = max(maxd, __shfl_xor(maxd, 4, 64));
    maxd = max(maxd, __shfl_xor(maxd, 8, 64));
    // maxd now uniform across the wave (quads hold identical degree sets)

    float ac[4][8];
    #pragma unroll
    for (int s = 0; s < 4; ++s)
        #pragma unroll
        for (int j = 0; j < 8; ++j) ac[s][j] = 0.f;

    const ushort_t* hbase = hin + quad * 8;   // this lane's feature chunk offset
    int e = 0;
    for (; e + 1 < maxd; e += 2) {
        bool on0 = e < deg, on1 = e + 1 < deg;
        int i0 = on0 ? beg + e : 0;
        int i1 = on1 ? beg + e + 1 : 0;
        int s0 = colsrc[i0];
        int s1 = colsrc[i1];
        float m0 = on0 ? 1.f : 0.f;
        float m1 = on1 ? 1.f : 0.f;
        const short8* h0 = (const short8*)(hbase + (size_t)s0 * 128);
        const short8* h1 = (const short8*)(hbase + (size_t)s1 * 128);
        short8 v0[4], v1[4];
        #pragma unroll
        for (int s = 0; s < 4; ++s) { v0[s] = h0[s * 4]; v1[s] = h1[s * 4]; }
        #pragma unroll
        for (int s = 0; s < 4; ++s)
            #pragma unroll
            for (int j = 0; j < 8; ++j) {
                ac[s][j] = fmaf(m0, bf2f((ushort_t)v0[s][j]), ac[s][j]);
                ac[s][j] = fmaf(m1, bf2f((ushort_t)v1[s][j]), ac[s][j]);
            }
    }
    if (e < maxd) {
        bool on0 = e < deg;
        int i0 = on0 ? beg + e : 0;
        int s0 = colsrc[i0];
        float m0 = on0 ? 1.f : 0.f;
        const short8* h0 = (const short8*)(hbase + (size_t)s0 * 128);
        #pragma unroll
        for (int s = 0; s < 4; ++s) {
            short8 v0 = h0[s * 4];
            #pragma unroll
            for (int j = 0; j < 8; ++j)
                ac[s][j] = fmaf(m0, bf2f((ushort_t)v0[j]), ac[s][j]);
        }
    }

    // BN affine (deferred from prev layer) + pack to bf16 A-fragments
    float degf = (float)deg;
    short8 afrag[4];
    #pragma unroll
    for (int s = 0; s < 4; ++s) {
        short8 av;
        #pragma unroll
        for (int j = 0; j < 8; ++j) {
            int f = s * 32 + quad * 8 + j;
            float val;
            if (stats != nullptr) {
                const float inv_n = 1.0f / (float)NN;
                float m = stats[f] * inv_n;
                float var = fmaf(-m, m, stats[HD + f] * inv_n);
                float sc = bng[f] * rsqrtf(var + 1e-5f);
                float sh = bnb[f] - m * sc;
                val = fmaf(sc, ac[s][j], degf * sh);
            } else {
                val = ac[s][j];
            }
            av[j] = (short)f2bf(val);
        }
        afrag[s] = av;
    }

    // MFMA phase (identical to verified R9 k_conv)
    floatx4 acc[8];
    #pragma unroll
    for (int c = 0; c < 8; ++c) acc[c] = (floatx4){0.f, 0.f, 0.f, 0.f};
    #pragma unroll
    for (int c = 0; c < 8; ++c) {
        size_t boff = (size_t)(16 * c + l15) * 128 + quad * 8;
        #pragma unroll
        for (int s = 0; s < 4; ++s) {
            short8 bf = *(const short8*)(Wt + boff + 32 * s);
            acc[c] = __builtin_amdgcn_mfma_f32_16x16x32_bf16(afrag[s], bf, acc[c], 0, 0, 0);
        }
    }

    __syncthreads();   // sstat zeroing visible before atomics
    int orow0 = rowbase + quad * 4;
    #pragma unroll
    for (int c = 0; c < 8; ++c) {
        int col = 16 * c + l15;
        float bv = bias[col];
        float ls = 0.f, lq = 0.f;
        #pragma unroll
        for (int i = 0; i < 4; ++i) {
            int r = orow0 + i;
            if (r < NN) {
                float v = fmaxf(acc[c][i] + bv, 0.f);
                ushort_t bb = f2bf(v);
                hout[(size_t)r * 128 + col] = bb;
                float vr = bf2f(bb);
                ls += vr;
                lq = fmaf(vr, vr, lq);
            }
        }
        ls += __shfl_xor(ls, 16, 64);
        ls += __shfl_xor(ls, 32, 64);
        lq += __shfl_xor(lq, 16, 64);
        lq += __shfl_xor(lq, 32, 64);
        if (quad == 0) {
            atomicAdd(&sstat[col], ls);
            atomicAdd(&sstat[128 + col], lq);
        }
    }
    __syncthreads();
    partials[(size_t)blockIdx.x * 256 + t] = sstat[t];
}

// ---------------- Partial-stats reduction: 1563 x 256 -> 256 (64 blocks) -----------

__global__ __launch_bounds__(256) void k_red(const float* __restrict__ partials,
                                             float* __restrict__ stats) {
    int t = threadIdx.x;
    float s = 0.f;
    for (int r = blockIdx.x; r < NB; r += 64) s += partials[(size_t)r * 256 + t];
    atomicAdd(&stats[t], s);
}

// ---------------- Pooling, phase 1: per-(graph,slice) partial sums (bf16 h) ---------

__device__ __forceinline__ int lowerb(const int* __restrict__ b, int n, int key) {
    int lo = 0, hi = n;
    while (lo < hi) {
        int mid = (lo + hi) >> 1;
        if (b[mid] < key) lo = mid + 1;
        else hi = mid;
    }
    return lo;
}

__global__ __launch_bounds__(256) void k_pool1(
    const ushort_t* __restrict__ h, const int* __restrict__ batch,
    float* __restrict__ ppart) {
    int g = blockIdx.x >> 4;
    int sl = blockIdx.x & (PSL - 1);
    int lo = lowerb(batch, NN, g);
    int hi = lowerb(batch, NN, g + 1);
    int cnt = hi - lo;
    int a = lo + (int)(((long long)cnt * sl) >> 4);
    int b = lo + (int)(((long long)cnt * (sl + 1)) >> 4);
    int wave = threadIdx.x >> 6, lane = threadIdx.x & 63;
    const ushort2* h2 = (const ushort2*)h;
    float ax = 0.f, ay = 0.f;
    for (int n = a + wave; n < b; n += 4) {
        ushort2 v = h2[(size_t)n * 64 + lane];
        ax += bf2f(v.x);
        ay += bf2f(v.y);
    }
    __shared__ float2 red[4][64];
    red[wave][lane] = make_float2(ax, ay);
    __syncthreads();
    if (wave == 0) {
        float sx = 0.f, sy = 0.f;
        for (int w = 0; w < 4; ++w) {
            sx += red[w][lane].x;
            sy += red[w][lane].y;
        }
        ((float2*)ppart)[(size_t)blockIdx.x * 64 + lane] = make_float2(sx, sy);
    }
}

// ---------------- Pooling, phase 2: combine slices + deferred BN affine ----------------

__global__ __launch_bounds__(64) void k_pool2(
    const float* __restrict__ ppart, const int* __restrict__ batch,
    const float* __restrict__ stats, const float* __restrict__ bng, const float* __restrict__ bnb,
    float* __restrict__ pooled) {
    int g = blockIdx.x;
    int lane = threadIdx.x;
    float sx = 0.f, sy = 0.f;
    #pragma unroll
    for (int s = 0; s < PSL; ++s) {
        float2 v = ((const float2*)ppart)[(size_t)(g * PSL + s) * 64 + lane];
        sx += v.x;
        sy += v.y;
    }
    int cnt = lowerb(batch, NN, g + 1) - lowerb(batch, NN, g);
    int c0 = lane * 2;
    const float inv_n = 1.0f / (float)NN;
    float m0 = stats[c0] * inv_n, m1 = stats[c0 + 1] * inv_n;
    float var0 = fmaf(-m0, m0, stats[HD + c0] * inv_n);
    float var1 = fmaf(-m1, m1, stats[HD + c0 + 1] * inv_n);
    float sc0 = bng[c0] * rsqrtf(var0 + 1e-5f);
    float sc1 = bng[c0 + 1] * rsqrtf(var1 + 1e-5f);
    float sh0 = bnb[c0] - m0 * sc0;
    float sh1 = bnb[c0 + 1] - m1 * sc1;
    float denom = fmaxf((float)cnt, 1.f);
    float2 o;
    o.x = (sc0 * sx + (float)cnt * sh0) / denom;
    o.y = (sc1 * sy + (float)cnt * sh1) / denom;
    ((float2*)pooled)[g * 64 + lane] = o;
}

// ---------------- MLP head + log_softmax (one wave per graph) ----------------

__global__ __launch_bounds__(64) void k_head(
    const float* __restrict__ pooled, const float* __restrict__ w1, const float* __restrict__ b1,
    const float* __restrict__ w2, const float* __restrict__ b2, float* __restrict__ out) {
    int g = blockIdx.x;
    int j = threadIdx.x;
    float hid = b1[j];
    const float* p = pooled + g * 128;
    #pragma unroll 8
    for (int k = 0; k < 128; ++k) hid = fmaf(p[k], w1[k * 64 + j], hid);
    float o[4];
    #pragma unroll
    for (int c = 0; c < 4; ++c) {
        float v = hid * w2[j * 4 + c];
        #pragma unroll
        for (int off = 1; off < 64; off <<= 1) v += __shfl_xor(v, off, 64);
        o[c] = v + b2[c];
    }
    if (j == 0) {
        float mx = fmaxf(fmaxf(o[0], o[1]), fmaxf(o[2], o[3]));
        float se = expf(o[0] - mx) + expf(o[1] - mx) + expf(o[2] - mx) + expf(o[3] - mx);
        float ls = mx + logf(se);
        #pragma unroll
        for (int c = 0; c < 4; ++c) out[g * 4 + c] = o[c] - ls;
    }
}

extern "C" void kernel_launch(void* const* d_in, const int* in_sizes, int n_in,
                              void* d_out, int out_size, void* d_ws, size_t ws_size,
                              hipStream_t stream) {
    const float* x = (const float*)d_in[0];
    const int* ei = (const int*)d_in[1];
    const int* batch = (const int*)d_in[2];
    const float* conv_w = (const float*)d_in[3];
    const float* conv_b = (const float*)d_in[4];
    const float* bn_g = (const float*)d_in[5];
    const float* bn_b = (const float*)d_in[6];
    const float* l1w = (const float*)d_in[7];
    const float* l1b = (const float*)d_in[8];
    const float* l2w = (const float*)d_in[9];
    const float* l2b = (const float*)d_in[10];
    float* out = (float*)d_out;
    (void)in_sizes; (void)n_in; (void)out_size; (void)ws_size;

    char* ws = (char*)d_ws;
    int* counts = (int*)(ws + 0);               // 400000 B
    int* cursor = (int*)(ws + 400000);          // 400000 B
    float* stats = (float*)(ws + 800000);       // 6*256 floats = 6144 B
    const size_t zero_bytes = 806144;           // counts + cursor + stats
    int* rowptr = (int*)(ws + 806144);          // 100001 ints
    int* bsums = (int*)(ws + 1206400);          // 391 ints
    int* colsrc = (int*)(ws + 1208192);         // 600000 ints -> ends 3608192
    float* pooled = (float*)(ws + 3608192);     // 64*128 floats -> ends 3640960
    float* ppart = (float*)(ws + 3641344);      // 1024*128 floats -> ends 4165632
    float* partials = (float*)(ws + 4165632);   // 1563*256 floats -> ends 5766144
    ushort_t* xb = (ushort_t*)(ws + 5766656);   // 25600000 B -> ends 31366656
    ushort_t* hb0 = (ushort_t*)(ws + 31366656); // 25600000 B -> ends 56966656
    ushort_t* hb1 = (ushort_t*)(ws + 56966656); // 25600000 B -> ends 82566656
    ushort_t* wtbuf = (ushort_t*)(ws + 82566656); // 196608 B -> ends 82763264

    hipMemsetAsync(ws, 0, zero_bytes, stream);

    k_cast<<<(NN * 32 + 255) / 256, 256, 0, stream>>>(x, xb);
    k_wcast<<<NL, 256, 0, stream>>>(conv_w, wtbuf);

    int ebl = (NE + 255) / 256;
    int nb1 = (NN + 255) / 256;  // 391
    k_hist<<<ebl, 256, 0, stream>>>(ei, counts);
    k_scan1<<<nb1, 256, 0, stream>>>(counts, bsums);
    k_scan2<<<1, 512, 0, stream>>>(bsums, nb1);
    k_scan3<<<nb1, 256, 0, stream>>>(counts, bsums, rowptr);
    k_fill<<<ebl, 256, 0, stream>>>(ei, rowptr, cursor, colsrc);

    // ping-pong h buffers: gconv reads hin, writes hout (never in place)
    ushort_t* hb[2] = {hb0, hb1};
    for (int L = 0; L < NL; ++L) {
        const ushort_t* hin = (L == 0) ? xb : hb[(L + 1) & 1];
        ushort_t* hout = hb[L & 1];
        const float* lstats = (L == 0) ? nullptr : (stats + (L - 1) * 256);
        const float* lg = (L == 0) ? nullptr : (bn_g + (L - 1) * 128);
        const float* lb = (L == 0) ? nullptr : (bn_b + (L - 1) * 128);
        k_gconv<<<NB, 256, 0, stream>>>(hin, rowptr, colsrc, lstats, lg, lb,
                                        wtbuf + L * 16384, conv_b + L * 128,
                                        hout, partials);
        k_red<<<64, 256, 0, stream>>>(partials, stats + L * 256);
    }
    // final h is hb[5&1] = hb1
    k_pool1<<<NG * PSL, 256, 0, stream>>>(hb1, batch, ppart);
    k_pool2<<<NG, 64, 0, stream>>>(ppart, batch, stats + 5 * 256, bn_g + 5 * 128, bn_b + 5 * 128, pooled);
    k_head<<<NG, 64, 0, stream>>>(pooled, l1w, l1b, l2w, l2b, out);
}

// Round 11
// 762.772 us; speedup vs baseline: 1.5596x; 1.0305x over previous
//
#include <hip/hip_runtime.h>
#include <math.h>

#define NN 100000
#define NE 600000
#define NG 64
#define HD 128
#define NL 6
#define NB 1563   // gconv blocks = ceil(NN/64)
#define PSL 16    // pool slices per graph

typedef unsigned short ushort_t;
typedef short short8 __attribute__((ext_vector_type(8)));
typedef float floatx4 __attribute__((ext_vector_type(4)));

__device__ __forceinline__ float bf2f(ushort_t u) {
    return __uint_as_float(((unsigned)u) << 16);
}
__device__ __forceinline__ ushort_t f2bf(float f) {
    unsigned u = __float_as_uint(f);
    unsigned r = (u + 0x7fffu + ((u >> 16) & 1u)) >> 16;   // round-to-nearest-even
    return (ushort_t)r;
}

// ---------------- x -> bf16 cast (once per call) ----------------

__global__ __launch_bounds__(256) void k_cast(const float* __restrict__ x,
                                              ushort_t* __restrict__ xb) {
    int i = blockIdx.x * 256 + threadIdx.x;
    if (i < NN * 32) {
        float4 v = ((const float4*)x)[i];
        ((ushort4*)xb)[i] = make_ushort4(f2bf(v.x), f2bf(v.y), f2bf(v.z), f2bf(v.w));
    }
}

// ---------------- W -> bf16 transpose: Wt[L][col][k] ----------------

__global__ __launch_bounds__(256) void k_wcast(const float* __restrict__ W,
                                               ushort_t* __restrict__ Wt) {
    const float* Wl = W + blockIdx.x * 16384;
    ushort_t* Wtl = Wt + blockIdx.x * 16384;
    for (int id = threadIdx.x; id < 16384; id += 256) {
        int k = id >> 7, c = id & 127;
        Wtl[c * 128 + k] = f2bf(Wl[id]);
    }
}

// ---------------- CSR build ----------------

__global__ __launch_bounds__(256) void k_hist(const int* __restrict__ ei, int* __restrict__ counts) {
    int e = blockIdx.x * 256 + threadIdx.x;
    if (e < NE) atomicAdd(&counts[ei[NE + e]], 1);
}

__global__ __launch_bounds__(256) void k_scan1(const int* __restrict__ counts, int* __restrict__ bsums) {
    __shared__ int s[256];
    int i = blockIdx.x * 256 + threadIdx.x;
    s[threadIdx.x] = (i < NN) ? counts[i] : 0;
    __syncthreads();
    for (int off = 128; off > 0; off >>= 1) {
        if (threadIdx.x < off) s[threadIdx.x] += s[threadIdx.x + off];
        __syncthreads();
    }
    if (threadIdx.x == 0) bsums[blockIdx.x] = s[0];
}

__global__ __launch_bounds__(512) void k_scan2(int* __restrict__ bsums, int nb) {
    __shared__ int s[512];
    int t = threadIdx.x;
    s[t] = (t < nb) ? bsums[t] : 0;
    __syncthreads();
    for (int off = 1; off < 512; off <<= 1) {
        int v = (t >= off) ? s[t - off] : 0;
        __syncthreads();
        s[t] += v;
        __syncthreads();
    }
    if (t < nb) bsums[t] = (t == 0) ? 0 : s[t - 1];
}

__global__ __launch_bounds__(256) void k_scan3(const int* __restrict__ counts, const int* __restrict__ bsums,
                                               int* __restrict__ rowptr) {
    __shared__ int s[256];
    int t = threadIdx.x;
    int i = blockIdx.x * 256 + t;
    int v = (i < NN) ? counts[i] : 0;
    s[t] = v;
    __syncthreads();
    for (int off = 1; off < 256; off <<= 1) {
        int u = (t >= off) ? s[t - off] : 0;
        __syncthreads();
        s[t] += u;
        __syncthreads();
    }
    if (i < NN) rowptr[i] = bsums[blockIdx.x] + s[t] - v;
    if (i == 0) rowptr[NN] = NE;
}

__global__ __launch_bounds__(256) void k_fill(const int* __restrict__ ei, const int* __restrict__ rowptr,
                                              int* __restrict__ cursor, int* __restrict__ colsrc) {
    int e = blockIdx.x * 256 + threadIdx.x;
    if (e < NE) {
        int d = ei[NE + e];
        int pos = rowptr[d] + atomicAdd(&cursor[d], 1);
        colsrc[pos] = ei[e];
    }
}

// ---------------- Degree sort (descending): counting sort into perm -------------
// Buckets = min(deg,63). LDS-aggregated histogram/cursor to avoid contended
// global atomics. Within-bucket order arbitrary (per-row math is order-exact).

__global__ __launch_bounds__(256) void k_dhist(const int* __restrict__ rowptr,
                                               int* __restrict__ dcount) {
    __shared__ int lc[64];
    int t = threadIdx.x;
    if (t < 64) lc[t] = 0;
    __syncthreads();
    int n = blockIdx.x * 256 + t;
    if (n < NN) {
        int d = rowptr[n + 1] - rowptr[n];
        atomicAdd(&lc[min(d, 63)], 1);
    }
    __syncthreads();
    if (t < 64 && lc[t] > 0) atomicAdd(&dcount[t], lc[t]);
}

__global__ __launch_bounds__(64) void k_dscan(const int* __restrict__ dcount,
                                              int* __restrict__ doff) {
    int t = threadIdx.x;   // descending: bucket 63 first
    int s = 0;
    for (int b = t + 1; b < 64; ++b) s += dcount[b];
    doff[t] = s;
}

__global__ __launch_bounds__(256) void k_dfill(const int* __restrict__ rowptr,
                                               const int* __restrict__ doff,
                                               int* __restrict__ dcursor,
                                               int* __restrict__ perm) {
    __shared__ int lc[64], lbase[64];
    int t = threadIdx.x;
    if (t < 64) lc[t] = 0;
    __syncthreads();
    int n = blockIdx.x * 256 + t;
    int b = 0, my = 0;
    if (n < NN) {
        int d = rowptr[n + 1] - rowptr[n];
        b = min(d, 63);
        my = atomicAdd(&lc[b], 1);
    }
    __syncthreads();
    if (t < 64 && lc[t] > 0) lbase[t] = atomicAdd(&dcursor[t], lc[t]);
    __syncthreads();
    if (n < NN) perm[doff[b] + lbase[b] + my] = n;
}

// ---------------- Fused gather->MFMA layer kernel (degree-sorted rows) ----------
// 64 rows/block via perm (descending degree -> uniform-degree waves, heavy blocks
// first). Gather lands directly in A-fragment layout: lane (l15,quad) accumulates
// row perm[base+l15], features {s*32+quad*8+j}, 2-way edge unroll (8 x 16-B loads
// in flight). BN affine in fp32 -> bf16 afrag. MFMA 16x16x32 bf16, D: col=lane&15,
// row=quad*4+reg. Store rows resolved via __shfl of the perm values.

__global__ __launch_bounds__(256) void k_gconv(
    const ushort_t* __restrict__ hin, const int* __restrict__ perm,
    const int* __restrict__ rowptr, const int* __restrict__ colsrc,
    const float* __restrict__ stats, const float* __restrict__ bng,
    const float* __restrict__ bnb,
    const ushort_t* __restrict__ Wt, const float* __restrict__ bias,
    ushort_t* __restrict__ hout, float* __restrict__ partials) {
    __shared__ float sstat[256];
    int t = threadIdx.x;
    sstat[t] = 0.f;
    int wave = t >> 6, lane = t & 63;
    int l15 = lane & 15, quad = lane >> 4;
    int rowbase = blockIdx.x * 64 + wave * 16;
    int idx = rowbase + l15;
    bool valid = idx < NN;
    int row = valid ? perm[idx] : 0;
    int beg = valid ? rowptr[row] : 0;
    int end = valid ? rowptr[row + 1] : 0;
    int deg = end - beg;
    int maxd = deg;
    maxd = max(maxd, __shfl_xor(maxd, 1, 64));
    maxd = max(maxd, __shfl_xor(maxd, 2, 64));
    maxd = max(maxd, __shfl_xor(maxd, 4, 64));
    maxd = max(maxd, __shfl_xor(maxd, 8, 64));

    float ac[4][8];
    #pragma unroll
    for (int s = 0; s < 4; ++s)
        #pragma unroll
        for (int j = 0; j < 8; ++j) ac[s][j] = 0.f;

    const ushort_t* hbase = hin + quad * 8;
    int e = 0;
    for (; e + 1 < maxd; e += 2) {
        bool on0 = e < deg, on1 = e + 1 < deg;
        int i0 = on0 ? beg + e : 0;
        int i1 = on1 ? beg + e + 1 : 0;
        int s0 = colsrc[i0];
        int s1 = colsrc[i1];
        float m0 = on0 ? 1.f : 0.f;
        float m1 = on1 ? 1.f : 0.f;
        const short8* h0 = (const short8*)(hbase + (size_t)s0 * 128);
        const short8* h1 = (const short8*)(hbase + (size_t)s1 * 128);
        short8 v0[4], v1[4];
        #pragma unroll
        for (int s = 0; s < 4; ++s) { v0[s] = h0[s * 4]; v1[s] = h1[s * 4]; }
        #pragma unroll
        for (int s = 0; s < 4; ++s)
            #pragma unroll
            for (int j = 0; j < 8; ++j) {
                ac[s][j] = fmaf(m0, bf2f((ushort_t)v0[s][j]), ac[s][j]);
                ac[s][j] = fmaf(m1, bf2f((ushort_t)v1[s][j]), ac[s][j]);
            }
    }
    if (e < maxd) {
        bool on0 = e < deg;
        int i0 = on0 ? beg + e : 0;
        int s0 = colsrc[i0];
        float m0 = on0 ? 1.f : 0.f;
        const short8* h0 = (const short8*)(hbase + (size_t)s0 * 128);
        #pragma unroll
        for (int s = 0; s < 4; ++s) {
            short8 v0 = h0[s * 4];
            #pragma unroll
            for (int j = 0; j < 8; ++j)
                ac[s][j] = fmaf(m0, bf2f((ushort_t)v0[j]), ac[s][j]);
        }
    }

    // BN affine (deferred from prev layer) + pack to bf16 A-fragments
    float degf = (float)deg;
    short8 afrag[4];
    #pragma unroll
    for (int s = 0; s < 4; ++s) {
        short8 av;
        #pragma unroll
        for (int j = 0; j < 8; ++j) {
            int f = s * 32 + quad * 8 + j;
            float val;
            if (stats != nullptr) {
                const float inv_n = 1.0f / (float)NN;
                float m = stats[f] * inv_n;
                float var = fmaf(-m, m, stats[HD + f] * inv_n);
                float sc = bng[f] * rsqrtf(var + 1e-5f);
                float sh = bnb[f] - m * sc;
                val = fmaf(sc, ac[s][j], degf * sh);
            } else {
                val = ac[s][j];
            }
            av[j] = (short)f2bf(val);
        }
        afrag[s] = av;
    }

    // MFMA phase
    floatx4 acc[8];
    #pragma unroll
    for (int c = 0; c < 8; ++c) acc[c] = (floatx4){0.f, 0.f, 0.f, 0.f};
    #pragma unroll
    for (int c = 0; c < 8; ++c) {
        size_t boff = (size_t)(16 * c + l15) * 128 + quad * 8;
        #pragma unroll
        for (int s = 0; s < 4; ++s) {
            short8 bf = *(const short8*)(Wt + boff + 32 * s);
            acc[c] = __builtin_amdgcn_mfma_f32_16x16x32_bf16(afrag[s], bf, acc[c], 0, 0, 0);
        }
    }

    // resolve this quad's 4 output rows (original node ids) from lane l15=quad*4+i
    int prow[4];
    #pragma unroll
    for (int i = 0; i < 4; ++i) prow[i] = __shfl(row, quad * 4 + i, 64);

    __syncthreads();   // sstat zeroing visible before atomics
    int orow0 = rowbase + quad * 4;
    #pragma unroll
    for (int c = 0; c < 8; ++c) {
        int col = 16 * c + l15;
        float bv = bias[col];
        float ls = 0.f, lq = 0.f;
        #pragma unroll
        for (int i = 0; i < 4; ++i) {
            if (orow0 + i < NN) {
                float v = fmaxf(acc[c][i] + bv, 0.f);
                ushort_t bb = f2bf(v);
                hout[(size_t)prow[i] * 128 + col] = bb;
                float vr = bf2f(bb);
                ls += vr;
                lq = fmaf(vr, vr, lq);
            }
        }
        ls += __shfl_xor(ls, 16, 64);
        ls += __shfl_xor(ls, 32, 64);
        lq += __shfl_xor(lq, 16, 64);
        lq += __shfl_xor(lq, 32, 64);
        if (quad == 0) {
            atomicAdd(&sstat[col], ls);
            atomicAdd(&sstat[128 + col], lq);
        }
    }
    __syncthreads();
    partials[(size_t)blockIdx.x * 256 + t] = sstat[t];
}

// ---------------- Partial-stats reduction: 1563 x 256 -> 256 (64 blocks) -----------

__global__ __launch_bounds__(256) void k_red(const float* __restrict__ partials,
                                             float* __restrict__ stats) {
    int t = threadIdx.x;
    float s = 0.f;
    for (int r = blockIdx.x; r < NB; r += 64) s += partials[(size_t)r * 256 + t];
    atomicAdd(&stats[t], s);
}

// ---------------- Pooling, phase 1: per-(graph,slice) partial sums (bf16 h) ---------

__device__ __forceinline__ int lowerb(const int* __restrict__ b, int n, int key) {
    int lo = 0, hi = n;
    while (lo < hi) {
        int mid = (lo + hi) >> 1;
        if (b[mid] < key) lo = mid + 1;
        else hi = mid;
    }
    return lo;
}

__global__ __launch_bounds__(256) void k_pool1(
    const ushort_t* __restrict__ h, const int* __restrict__ batch,
    float* __restrict__ ppart) {
    int g = blockIdx.x >> 4;
    int sl = blockIdx.x & (PSL - 1);
    int lo = lowerb(batch, NN, g);
    int hi = lowerb(batch, NN, g + 1);
    int cnt = hi - lo;
    int a = lo + (int)(((long long)cnt * sl) >> 4);
    int b = lo + (int)(((long long)cnt * (sl + 1)) >> 4);
    int wave = threadIdx.x >> 6, lane = threadIdx.x & 63;
    const ushort2* h2 = (const ushort2*)h;
    float ax = 0.f, ay = 0.f;
    for (int n = a + wave; n < b; n += 4) {
        ushort2 v = h2[(size_t)n * 64 + lane];
        ax += bf2f(v.x);
        ay += bf2f(v.y);
    }
    __shared__ float2 red[4][64];
    red[wave][lane] = make_float2(ax, ay);
    __syncthreads();
    if (wave == 0) {
        float sx = 0.f, sy = 0.f;
        for (int w = 0; w < 4; ++w) {
            sx += red[w][lane].x;
            sy += red[w][lane].y;
        }
        ((float2*)ppart)[(size_t)blockIdx.x * 64 + lane] = make_float2(sx, sy);
    }
}

// ---------------- Pooling, phase 2: combine slices + deferred BN affine ----------------

__global__ __launch_bounds__(64) void k_pool2(
    const float* __restrict__ ppart, const int* __restrict__ batch,
    const float* __restrict__ stats, const float* __restrict__ bng, const float* __restrict__ bnb,
    float* __restrict__ pooled) {
    int g = blockIdx.x;
    int lane = threadIdx.x;
    float sx = 0.f, sy = 0.f;
    #pragma unroll
    for (int s = 0; s < PSL; ++s) {
        float2 v = ((const float2*)ppart)[(size_t)(g * PSL + s) * 64 + lane];
        sx += v.x;
        sy += v.y;
    }
    int cnt = lowerb(batch, NN, g + 1) - lowerb(batch, NN, g);
    int c0 = lane * 2;
    const float inv_n = 1.0f / (float)NN;
    float m0 = stats[c0] * inv_n, m1 = stats[c0 + 1] * inv_n;
    float var0 = fmaf(-m0, m0, stats[HD + c0] * inv_n);
    float var1 = fmaf(-m1, m1, stats[HD + c0 + 1] * inv_n);
    float sc0 = bng[c0] * rsqrtf(var0 + 1e-5f);
    float sc1 = bng[c0 + 1] * rsqrtf(var1 + 1e-5f);
    float sh0 = bnb[c0] - m0 * sc0;
    float sh1 = bnb[c0 + 1] - m1 * sc1;
    float denom = fmaxf((float)cnt, 1.f);
    float2 o;
    o.x = (sc0 * sx + (float)cnt * sh0) / denom;
    o.y = (sc1 * sy + (float)cnt * sh1) / denom;
    ((float2*)pooled)[g * 64 + lane] = o;
}

// ---------------- MLP head + log_softmax (one wave per graph) ----------------

__global__ __launch_bounds__(64) void k_head(
    const float* __restrict__ pooled, const float* __restrict__ w1, const float* __restrict__ b1,
    const float* __restrict__ w2, const float* __restrict__ b2, float* __restrict__ out) {
    int g = blockIdx.x;
    int j = threadIdx.x;
    float hid = b1[j];
    const float* p = pooled + g * 128;
    #pragma unroll 8
    for (int k = 0; k < 128; ++k) hid = fmaf(p[k], w1[k * 64 + j], hid);
    float o[4];
    #pragma unroll
    for (int c = 0; c < 4; ++c) {
        float v = hid * w2[j * 4 + c];
        #pragma unroll
        for (int off = 1; off < 64; off <<= 1) v += __shfl_xor(v, off, 64);
        o[c] = v + b2[c];
    }
    if (j == 0) {
        float mx = fmaxf(fmaxf(o[0], o[1]), fmaxf(o[2], o[3]));
        float se = expf(o[0] - mx) + expf(o[1] - mx) + expf(o[2] - mx) + expf(o[3] - mx);
        float ls = mx + logf(se);
        #pragma unroll
        for (int c = 0; c < 4; ++c) out[g * 4 + c] = o[c] - ls;
    }
}

extern "C" void kernel_launch(void* const* d_in, const int* in_sizes, int n_in,
                              void* d_out, int out_size, void* d_ws, size_t ws_size,
                              hipStream_t stream) {
    const float* x = (const float*)d_in[0];
    const int* ei = (const int*)d_in[1];
    const int* batch = (const int*)d_in[2];
    const float* conv_w = (const float*)d_in[3];
    const float* conv_b = (const float*)d_in[4];
    const float* bn_g = (const float*)d_in[5];
    const float* bn_b = (const float*)d_in[6];
    const float* l1w = (const float*)d_in[7];
    const float* l1b = (const float*)d_in[8];
    const float* l2w = (const float*)d_in[9];
    const float* l2b = (const float*)d_in[10];
    float* out = (float*)d_out;
    (void)in_sizes; (void)n_in; (void)out_size; (void)ws_size;

    char* ws = (char*)d_ws;
    // counts region (dead after k_scan3) is reused for degree-sort counters;
    // cursor region (dead after k_fill) is reused for perm (NN*4 = 400000 B exactly).
    int* counts = (int*)(ws + 0);               // 400000 B
    int* dcount = (int*)(ws + 0);               // 256 B   (after k_fill)
    int* dcursor = (int*)(ws + 256);            // 256 B
    int* doff = (int*)(ws + 512);               // 256 B
    int* cursor = (int*)(ws + 400000);          // 400000 B
    int* perm = (int*)(ws + 400000);            // reuse   (after k_fill)
    float* stats = (float*)(ws + 800000);       // 6*256 floats = 6144 B
    const size_t zero_bytes = 806144;           // counts + cursor + stats
    int* rowptr = (int*)(ws + 806144);          // 100001 ints
    int* bsums = (int*)(ws + 1206400);          // 391 ints
    int* colsrc = (int*)(ws + 1208192);         // 600000 ints -> ends 3608192
    float* pooled = (float*)(ws + 3608192);     // 64*128 floats -> ends 3640960
    float* ppart = (float*)(ws + 3641344);      // 1024*128 floats -> ends 4165632
    float* partials = (float*)(ws + 4165632);   // 1563*256 floats -> ends 5766144
    ushort_t* xb = (ushort_t*)(ws + 5766656);   // 25600000 B -> ends 31366656
    ushort_t* hb0 = (ushort_t*)(ws + 31366656); // 25600000 B -> ends 56966656
    ushort_t* hb1 = (ushort_t*)(ws + 56966656); // 25600000 B -> ends 82566656
    ushort_t* wtbuf = (ushort_t*)(ws + 82566656); // 196608 B -> ends 82763264

    hipMemsetAsync(ws, 0, zero_bytes, stream);

    k_cast<<<(NN * 32 + 255) / 256, 256, 0, stream>>>(x, xb);
    k_wcast<<<NL, 256, 0, stream>>>(conv_w, wtbuf);

    int ebl = (NE + 255) / 256;
    int nb1 = (NN + 255) / 256;  // 391
    k_hist<<<ebl, 256, 0, stream>>>(ei, counts);
    k_scan1<<<nb1, 256, 0, stream>>>(counts, bsums);
    k_scan2<<<1, 512, 0, stream>>>(bsums, nb1);
    k_scan3<<<nb1, 256, 0, stream>>>(counts, bsums, rowptr);
    k_fill<<<ebl, 256, 0, stream>>>(ei, rowptr, cursor, colsrc);

    // degree counting sort (descending) into perm
    hipMemsetAsync(ws, 0, 512, stream);   // dcount + dcursor
    k_dhist<<<nb1, 256, 0, stream>>>(rowptr, dcount);
    k_dscan<<<1, 64, 0, stream>>>(dcount, doff);
    k_dfill<<<nb1, 256, 0, stream>>>(rowptr, doff, dcursor, perm);

    // ping-pong h buffers: gconv reads hin, writes hout (never in place)
    ushort_t* hb[2] = {hb0, hb1};
    for (int L = 0; L < NL; ++L) {
        const ushort_t* hin = (L == 0) ? xb : hb[(L + 1) & 1];
        ushort_t* hout = hb[L & 1];
        const float* lstats = (L == 0) ? nullptr : (stats + (L - 1) * 256);
        const float* lg = (L == 0) ? nullptr : (bn_g + (L - 1) * 128);
        const float* lb = (L == 0) ? nullptr : (bn_b + (L - 1) * 128);
        k_gconv<<<NB, 256, 0, stream>>>(hin, perm, rowptr, colsrc, lstats, lg, lb,
                                        wtbuf + L * 16384, conv_b + L * 128,
                                        hout, partials);
        k_red<<<64, 256, 0, stream>>>(partials, stats + L * 256);
    }
    // final h is hb[5&1] = hb1
    k_pool1<<<NG * PSL, 256, 0, stream>>>(hb1, batch, ppart);
    k_pool2<<<NG, 64, 0, stream>>>(ppart, batch, stats + 5 * 256, bn_g + 5 * 128, bn_b + 5 * 128, pooled);
    k_head<<<NG, 64, 0, stream>>>(pooled, l1w, l1b, l2w, l2b, out);
}